// Round 1
// baseline (379.752 us; speedup 1.0000x reference)
//
#include <hip/hip_runtime.h>
#include <hip/hip_bf16.h>

#define B_ROWS 65536
#define XD 362

typedef __bf16 bf16;
typedef __attribute__((ext_vector_type(8))) __bf16 bf16x8;
typedef __attribute__((ext_vector_type(4))) float f32x4;

// ---- workspace layout (bytes, all offsets 256-aligned) ----
// W1t [3][112][32] bf16  : n<100,k<6 -> W1[a][k][n]; k==6 -> b1; else 0
// W2t [3][400][128] bf16 : k<100 -> W2[a][k][n]; k==100 -> b2; else 0
// W3t [3][112][416] bf16 : n<100 (k<400 -> W3[a][k][n]; k==400 -> b3); else 0
// W4t [3][16][128] bf16  : n<6 (k<100 -> W4[a][k][n]; k==100 -> b4); else 0
#define OFF_W1T   0u
#define OFF_W2T   21504u
#define OFF_W3T   328704u
#define OFF_W4T   608256u
#define OFF_CNT   620544u
#define OFF_ACC   620800u
#define OFF_ATTC  621056u      // [3][65536][8] bf16 (6 att vals, 1.0, 0)
#define OFF_DELTA 3766784u     // [3][65536][6] f32

__global__ __launch_bounds__(256) void k_wprep(
    const float* __restrict__ W1, const float* __restrict__ b1,
    const float* __restrict__ W2, const float* __restrict__ b2,
    const float* __restrict__ W3, const float* __restrict__ b3,
    const float* __restrict__ W4, const float* __restrict__ b4,
    bf16* __restrict__ W1t, bf16* __restrict__ W2t,
    bf16* __restrict__ W3t, bf16* __restrict__ W4t,
    int* __restrict__ cnt, double* __restrict__ acc)
{
  int i = blockIdx.x * 256 + threadIdx.x;
  if (i == 0) { cnt[0] = 0; cnt[1] = 0; cnt[2] = 0; acc[0] = 0.0; }
  if (i < 3*400*128) {               // W2t
    int k = i & 127; int rn = i >> 7; int n = rn % 400; int a = rn / 400;
    float v = 0.f;
    if (k < 100) v = W2[(a*100 + k)*400 + n];
    else if (k == 100) v = b2[a*400 + n];
    W2t[i] = (bf16)v;
  }
  if (i < 3*112*416) {               // W3t
    int k = i % 416; int rn = i / 416; int n = rn % 112; int a = rn / 112;
    float v = 0.f;
    if (n < 100) {
      if (k < 400) v = W3[(a*400 + k)*100 + n];
      else if (k == 400) v = b3[a*100 + n];
    }
    W3t[i] = (bf16)v;
  }
  if (i < 3*112*32) {                // W1t
    int k = i & 31; int rn = i >> 5; int n = rn % 112; int a = rn / 112;
    float v = 0.f;
    if (n < 100) {
      if (k < 6) v = W1[(a*6 + k)*100 + n];
      else if (k == 6) v = b1[a*100 + n];
    }
    W1t[i] = (bf16)v;
  }
  if (i < 3*16*128) {                // W4t
    int k = i & 127; int rn = i >> 7; int n = rn & 15; int a = rn >> 4;
    float v = 0.f;
    if (n < 6) {
      if (k < 100) v = W4[(a*100 + k)*6 + n];
      else if (k == 100) v = b4[a*6 + n];
    }
    W4t[i] = (bf16)v;
  }
}

// One wave scans one row (16 rows per wave, 64 rows per block); compact rows
// per action with block-aggregated atomics (3 atomics/block, not 1/row).
__global__ __launch_bounds__(256) void k_gather(
    const float* __restrict__ x, const float* __restrict__ xn,
    const int* __restrict__ act,
    bf16* __restrict__ attC, float* __restrict__ deltaC, int* __restrict__ cnt)
{
  __shared__ float s_att[64][6];
  __shared__ float s_dlt[64][6];
  __shared__ int s_act[64];
  __shared__ int s_slot[64];
  int wv = threadIdx.x >> 6, lane = threadIdx.x & 63;
  int rowBase = blockIdx.x << 6;
  for (int rr = 0; rr < 16; ++rr) {
    int r = (wv << 4) + rr;
    int row = rowBase + r;
    const float* xr = x + (size_t)row * XD;
    int found = 1 << 30;
    for (int i = lane; i < XD; i += 64) {
      float v = xr[i];
      if (v == 10.0f && i < found) found = i;
    }
#pragma unroll
    for (int off = 32; off; off >>= 1) {
      int o = __shfl_xor(found, off);
      found = found < o ? found : o;
    }
    int p = found;
    if (p > XD - 1) p = 20;   // safety; reference guarantees a sentinel
    if (lane < 6) {
      int cell;
      switch (lane) {
        case 0: cell = 0;      break;
        case 1: cell = p;      break;
        case 2: cell = p - 19; break;
        case 3: cell = p + 19; break;
        case 4: cell = p - 1;  break;
        default: cell = p + 1; break;
      }
      float av = x[(size_t)row * XD + cell];
      float nv = xn[(size_t)row * XD + cell];
      s_att[r][lane] = av;
      s_dlt[r][lane] = nv - av;
    }
    if (lane == 6) s_act[r] = act[row];
  }
  __syncthreads();
  if (threadIdx.x < 64) {   // wave 0: rank rows within block, 3 atomics total
    int r = threadIdx.x;
    int ar = s_act[r];
    unsigned long long m0 = __ballot(ar == 0);
    unsigned long long m1 = __ballot(ar == 1);
    unsigned long long m2 = __ballot(ar == 2);
    int g0 = 0, g1 = 0, g2 = 0;
    if (r == 0) g0 = atomicAdd(&cnt[0], (int)__popcll(m0));
    if (r == 1) g1 = atomicAdd(&cnt[1], (int)__popcll(m1));
    if (r == 2) g2 = atomicAdd(&cnt[2], (int)__popcll(m2));
    g0 = __shfl(g0, 0); g1 = __shfl(g1, 1); g2 = __shfl(g2, 2);
    unsigned long long mm = (ar == 0) ? m0 : (ar == 1) ? m1 : m2;
    int base = (ar == 0) ? g0 : (ar == 1) ? g1 : g2;
    s_slot[r] = base + (int)__popcll(mm & ((1ull << r) - 1ull));
  }
  __syncthreads();
  int t = threadIdx.x;
  int r = t >> 2, j = t & 3;
  int ar = s_act[r];
  size_t rb = (size_t)ar * B_ROWS + s_slot[r];
  float e0 = (2*j < 6) ? s_att[r][2*j] : (2*j == 6 ? 1.0f : 0.0f);
  float e1 = (2*j + 1 < 6) ? s_att[r][2*j + 1] : 0.0f;
  attC[rb*8 + 2*j]     = (bf16)e0;
  attC[rb*8 + 2*j + 1] = (bf16)e1;
  if (j < 3) {
    deltaC[rb*6 + 2*j]     = s_dlt[r][2*j];
    deltaC[rb*6 + 2*j + 1] = s_dlt[r][2*j + 1];
  }
}

// 64 rows per block, 4 waves x one 16-row m-tile; all layers via
// mfma_f32_16x16x32_bf16. A layout: m=lane&15, k=(lane>>4)*8+j.
// C/D layout: col=lane&15, row=(lane>>4)*4+reg. Bias folded as k-row
// (activation carries trailing 1.0). h3 reuses h1 buffer.
__global__ __launch_bounds__(256) void k_mlp(
    const bf16* __restrict__ W1t, const bf16* __restrict__ W2t,
    const bf16* __restrict__ W3t, const bf16* __restrict__ W4t,
    const bf16* __restrict__ attC, const float* __restrict__ deltaC,
    const int* __restrict__ cnt, double* __restrict__ acc)
{
  int a = blockIdx.y;
  int count = cnt[a];
  int start = blockIdx.x << 6;
  if (start >= count) return;
  __shared__ bf16 h1[64][136];   // 100 used, k-pad to 128, +8 row pad (2-way bank alias = free)
  __shared__ bf16 h2[64][424];   // 400 used +1 bias +pad to 416, +8 row pad
  __shared__ float s_part[4];
  int wv = threadIdx.x >> 6, lane = threadIdx.x & 63;
  int q = lane >> 4, c = lane & 15;

  // zero the pad columns (avoid NaN garbage feeding MFMA); h2 col 400 = 1.0 (bias row)
  for (int i = threadIdx.x; i < 64*24; i += 256) {
    int r = i / 24, cc = i % 24;
    h1[r][112 + cc] = (bf16)0.0f;
    h2[r][400 + cc] = (cc == 0) ? (bf16)1.0f : (bf16)0.0f;
  }
  __syncthreads();

  const bf16* W1a = W1t + a*112*32;
  const bf16* W2a = W2t + a*400*128;
  const bf16* W3a = W3t + a*112*416;
  const bf16* W4a = W4t + a*16*128;

  // ---- L1: 6(+bias)->100, K=32 (one kstep), N=112 (7 ntiles) ----
  bf16x8 aAtt;
#pragma unroll
  for (int i = 0; i < 8; ++i) aAtt[i] = (bf16)0.0f;
  {
    int slot = start + (wv << 4) + c;          // A m-index = lane&15
    if (q == 0 && slot < count)
      aAtt = *(const bf16x8*)(attC + ((size_t)a * B_ROWS + slot) * 8);
  }
#pragma unroll
  for (int nt = 0; nt < 7; ++nt) {
    bf16x8 b = *(const bf16x8*)(W1a + (nt*16 + c)*32 + q*8);
    f32x4 C = {0.f, 0.f, 0.f, 0.f};
    C = __builtin_amdgcn_mfma_f32_16x16x32_bf16(aAtt, b, C, 0, 0, 0);
    int n = nt*16 + c;
#pragma unroll
    for (int rg = 0; rg < 4; ++rg) {
      float v = (n < 100) ? (C[rg] > 0.f ? C[rg] : 0.f)
                          : (n == 100 ? 1.0f : 0.0f);   // bias marker for L2
      h1[(wv<<4) + q*4 + rg][n] = (bf16)v;
    }
  }
  __syncthreads();

  // ---- L2: 100(+bias)->400, K=128 (4 ksteps), N=400 (25 ntiles) ----
  bf16x8 A2[4];
#pragma unroll
  for (int t = 0; t < 4; ++t)
    A2[t] = *(const bf16x8*)&h1[(wv<<4) + c][t*32 + q*8];
#pragma unroll 1
  for (int nt = 0; nt < 25; ++nt) {
    f32x4 C = {0.f, 0.f, 0.f, 0.f};
#pragma unroll
    for (int t = 0; t < 4; ++t) {
      bf16x8 b = *(const bf16x8*)(W2a + (nt*16 + c)*128 + t*32 + q*8);
      C = __builtin_amdgcn_mfma_f32_16x16x32_bf16(A2[t], b, C, 0, 0, 0);
    }
    int n = nt*16 + c;
#pragma unroll
    for (int rg = 0; rg < 4; ++rg) {
      float v = C[rg] > 0.f ? C[rg] : 0.f;
      h2[(wv<<4) + q*4 + rg][n] = (bf16)v;
    }
  }
  __syncthreads();

  // ---- L3: 400(+bias)->100, K=416 (13 ksteps), N=112 (7 ntiles) ----
  bf16x8 A3[13];
#pragma unroll
  for (int t = 0; t < 13; ++t)
    A3[t] = *(const bf16x8*)&h2[(wv<<4) + c][t*32 + q*8];
#pragma unroll 1
  for (int nt = 0; nt < 7; ++nt) {
    f32x4 C = {0.f, 0.f, 0.f, 0.f};
#pragma unroll
    for (int t = 0; t < 13; ++t) {
      bf16x8 b = *(const bf16x8*)(W3a + (nt*16 + c)*416 + t*32 + q*8);
      C = __builtin_amdgcn_mfma_f32_16x16x32_bf16(A3[t], b, C, 0, 0, 0);
    }
    int n = nt*16 + c;
#pragma unroll
    for (int rg = 0; rg < 4; ++rg) {
      float v = (n < 100) ? (C[rg] > 0.f ? C[rg] : 0.f)
                          : (n == 100 ? 1.0f : 0.0f);   // bias marker for L4
      h1[(wv<<4) + q*4 + rg][n] = (bf16)v;              // h3 reuses h1
    }
  }
  __syncthreads();

  // ---- L4: 100(+bias)->6, K=128 (4 ksteps), N=16 (1 ntile) + MSE ----
  bf16x8 A4[4];
#pragma unroll
  for (int t = 0; t < 4; ++t)
    A4[t] = *(const bf16x8*)&h1[(wv<<4) + c][t*32 + q*8];
  f32x4 C4 = {0.f, 0.f, 0.f, 0.f};
#pragma unroll
  for (int t = 0; t < 4; ++t) {
    bf16x8 b = *(const bf16x8*)(W4a + c*128 + t*32 + q*8);
    C4 = __builtin_amdgcn_mfma_f32_16x16x32_bf16(A4[t], b, C4, 0, 0, 0);
  }
  float sq = 0.f;
  if (c < 6) {
#pragma unroll
    for (int rg = 0; rg < 4; ++rg) {
      int slot = start + (wv<<4) + q*4 + rg;
      if (slot < count) {
        float d = deltaC[((size_t)a * B_ROWS + slot)*6 + c];
        float e = C4[rg] - d;
        sq += e * e;
      }
    }
  }
#pragma unroll
  for (int off = 32; off; off >>= 1) sq += __shfl_xor(sq, off);
  if (lane == 0) s_part[wv] = sq;
  __syncthreads();
  if (threadIdx.x == 0) {
    float tot = s_part[0] + s_part[1] + s_part[2] + s_part[3];
    atomicAdd(acc, (double)tot);
  }
}

__global__ void k_final(const double* __restrict__ acc, float* __restrict__ out)
{
  out[0] = (float)(acc[0] / (double)(B_ROWS * 6));
}

extern "C" void kernel_launch(void* const* d_in, const int* in_sizes, int n_in,
                              void* d_out, int out_size, void* d_ws, size_t ws_size,
                              hipStream_t stream)
{
  const float* x  = (const float*)d_in[0];
  const float* xn = (const float*)d_in[1];
  const int*  act = (const int*)d_in[2];
  const float* W1 = (const float*)d_in[3];
  const float* b1 = (const float*)d_in[4];
  const float* W2 = (const float*)d_in[5];
  const float* b2 = (const float*)d_in[6];
  const float* W3 = (const float*)d_in[7];
  const float* b3 = (const float*)d_in[8];
  const float* W4 = (const float*)d_in[9];
  const float* b4 = (const float*)d_in[10];

  char* ws = (char*)d_ws;
  bf16*   W1t    = (bf16*)(ws + OFF_W1T);
  bf16*   W2t    = (bf16*)(ws + OFF_W2T);
  bf16*   W3t    = (bf16*)(ws + OFF_W3T);
  bf16*   W4t    = (bf16*)(ws + OFF_W4T);
  int*    cnt    = (int*)(ws + OFF_CNT);
  double* acc    = (double*)(ws + OFF_ACC);
  bf16*   attC   = (bf16*)(ws + OFF_ATTC);
  float*  deltaC = (float*)(ws + OFF_DELTA);

  k_wprep<<<dim3(600), dim3(256), 0, stream>>>(W1, b1, W2, b2, W3, b3, W4, b4,
                                               W1t, W2t, W3t, W4t, cnt, acc);
  k_gather<<<dim3(B_ROWS/64), dim3(256), 0, stream>>>(x, xn, act, attC, deltaC, cnt);
  k_mlp<<<dim3(B_ROWS/64, 3), dim3(256), 0, stream>>>(W1t, W2t, W3t, W4t,
                                                      attC, deltaC, cnt, acc);
  k_final<<<dim3(1), dim3(1), 0, stream>>>(acc, (float*)d_out);
}

// Round 2
// 337.190 us; speedup vs baseline: 1.1262x; 1.1262x over previous
//
#include <hip/hip_runtime.h>
#include <hip/hip_bf16.h>

#define B_ROWS 65536
#define XD 362

typedef __bf16 bf16;
typedef __attribute__((ext_vector_type(8))) __bf16 bf16x8;
typedef __attribute__((ext_vector_type(4))) float f32x4;
typedef __attribute__((ext_vector_type(2))) float f32x2;

// ---- workspace layout (bytes) ----
#define OFF_W1T   0u          // [3][112][32] bf16
#define OFF_W2T   21504u      // [3][400][128] bf16
#define OFF_W3T   328704u     // [3][112][416] bf16
#define OFF_W4T   608256u     // [3][16][128] bf16
#define OFF_CNT   620544u     // int[3]
#define OFF_ACC   620800u     // double
#define OFF_PTR   621056u     // int[65536]
#define OFF_ATTC  883200u     // [3][65536][8] bf16
#define OFF_DELTA 4028928u    // [3][65536][6] f32  (end ~8.75 MB)

__global__ __launch_bounds__(256) void k_wprep(
    const float* __restrict__ W1, const float* __restrict__ b1,
    const float* __restrict__ W2, const float* __restrict__ b2,
    const float* __restrict__ W3, const float* __restrict__ b3,
    const float* __restrict__ W4, const float* __restrict__ b4,
    bf16* __restrict__ W1t, bf16* __restrict__ W2t,
    bf16* __restrict__ W3t, bf16* __restrict__ W4t,
    int* __restrict__ cnt, double* __restrict__ acc, int* __restrict__ ptrArr)
{
  int i = blockIdx.x * 256 + threadIdx.x;
  if (i == 0) { cnt[0] = 0; cnt[1] = 0; cnt[2] = 0; acc[0] = 0.0; }
  if (i < B_ROWS) ptrArr[i] = 0x7FFFFFFF;
  if (i < 3*400*128) {               // W2t [n=400][k=128]
    int k = i & 127; int rn = i >> 7; int n = rn % 400; int a = rn / 400;
    float v = 0.f;
    if (k < 100) v = W2[(a*100 + k)*400 + n];
    else if (k == 100) v = b2[a*400 + n];
    W2t[i] = (bf16)v;
  }
  if (i < 3*112*416) {               // W3t [n=112][k=416]
    int k = i % 416; int rn = i / 416; int n = rn % 112; int a = rn / 112;
    float v = 0.f;
    if (n < 100) {
      if (k < 400) v = W3[(a*400 + k)*100 + n];
      else if (k == 400) v = b3[a*100 + n];
    }
    W3t[i] = (bf16)v;
  }
  if (i < 3*112*32) {                // W1t [n=112][k=32]
    int k = i & 31; int rn = i >> 5; int n = rn % 112; int a = rn / 112;
    float v = 0.f;
    if (n < 100) {
      if (k < 6) v = W1[(a*6 + k)*100 + n];
      else if (k == 6) v = b1[a*100 + n];
    }
    W1t[i] = (bf16)v;
  }
  if (i < 3*16*128) {                // W4t [n=16][k=128]
    int k = i & 127; int rn = i >> 7; int n = rn & 15; int a = rn >> 4;
    float v = 0.f;
    if (n < 6) {
      if (k < 100) v = W4[(a*100 + k)*6 + n];
      else if (k == 100) v = b4[a*6 + n];
    }
    W4t[i] = (bf16)v;
  }
}

// Flat vectorized sentinel scan: float4 per thread-iter, rare atomicMin on hit.
#define SCAN_BLOCKS 2896   // 2896*256*8 float4 == 65536*362/4 exactly
__global__ __launch_bounds__(256) void k_scan(
    const float* __restrict__ x, int* __restrict__ ptrArr)
{
  int gid = blockIdx.x * 256 + threadIdx.x;
  const float4* x4 = (const float4*)x;
  const int total4 = B_ROWS * XD / 4;
#pragma unroll 2
  for (int i = gid; i < total4; i += SCAN_BLOCKS * 256) {
    float4 v = x4[i];
    if (v.x == 10.0f || v.y == 10.0f || v.z == 10.0f || v.w == 10.0f) {
      int flat = i * 4;
      if (v.x == 10.0f) atomicMin(&ptrArr[(flat    ) / XD], (flat    ) % XD);
      if (v.y == 10.0f) atomicMin(&ptrArr[(flat + 1) / XD], (flat + 1) % XD);
      if (v.z == 10.0f) atomicMin(&ptrArr[(flat + 2) / XD], (flat + 2) % XD);
      if (v.w == 10.0f) atomicMin(&ptrArr[(flat + 3) / XD], (flat + 3) % XD);
    }
  }
}

// One thread per row: gather 6 cells from x/xn (x is L3-hot after k_scan),
// per-wave ballot compaction into action-sorted arrays (3 atomics/wave).
__global__ __launch_bounds__(256) void k_gather2(
    const float* __restrict__ x, const float* __restrict__ xn,
    const int* __restrict__ act, const int* __restrict__ ptrArr,
    bf16* __restrict__ attC, float* __restrict__ deltaC, int* __restrict__ cnt)
{
  int row = blockIdx.x * 256 + threadIdx.x;
  int lane = threadIdx.x & 63;
  int p = ptrArr[row];
  if (p < 20 || p > 342) p = 20;   // reference guarantees 20..342
  const float* xr = x  + (size_t)row * XD;
  const float* nr = xn + (size_t)row * XD;
  int cells[6] = {0, p, p - 19, p + 19, p - 1, p + 1};
  float av[6], dv[6];
#pragma unroll
  for (int i = 0; i < 6; ++i) {
    av[i] = xr[cells[i]];
    dv[i] = nr[cells[i]] - av[i];
  }
  int a = act[row];
  unsigned long long m0 = __ballot(a == 0);
  unsigned long long m1 = __ballot(a == 1);
  unsigned long long m2 = __ballot(a == 2);
  int b0 = 0, b1 = 0, b2 = 0;
  if (lane == 0) {
    b0 = atomicAdd(&cnt[0], (int)__popcll(m0));
    b1 = atomicAdd(&cnt[1], (int)__popcll(m1));
    b2 = atomicAdd(&cnt[2], (int)__popcll(m2));
  }
  b0 = __shfl(b0, 0); b1 = __shfl(b1, 0); b2 = __shfl(b2, 0);
  unsigned long long lt = (1ull << lane) - 1ull;
  unsigned long long ma = (a == 0) ? m0 : (a == 1) ? m1 : m2;
  int base            = (a == 0) ? b0 : (a == 1) ? b1 : b2;
  int slot = base + (int)__popcll(ma & lt);
  size_t rb = (size_t)a * B_ROWS + slot;
  bf16x8 av8;
#pragma unroll
  for (int i = 0; i < 6; ++i) av8[i] = (bf16)av[i];
  av8[6] = (bf16)1.0f;   // bias marker
  av8[7] = (bf16)0.0f;
  *(bf16x8*)(attC + rb * 8) = av8;
  f32x2 d01 = {dv[0], dv[1]}, d23 = {dv[2], dv[3]}, d45 = {dv[4], dv[5]};
  *(f32x2*)(deltaC + rb * 6)     = d01;
  *(f32x2*)(deltaC + rb * 6 + 2) = d23;
  *(f32x2*)(deltaC + rb * 6 + 4) = d45;
}

// 64 rows/block, 4 waves x one 16-row m-tile. L2->L3 fused through a tiny
// per-wave LDS transpose chunk (within-wave only: DS pipe is in-order per
// wave; sched_barrier pins compiler ordering). No __syncthreads in main loop.
// A layout: m=lane&15, k=q*8+j. C/D layout: n=lane&15, m=q*4+reg.
__global__ __launch_bounds__(256) void k_mlp(
    const bf16* __restrict__ W1t, const bf16* __restrict__ W2t,
    const bf16* __restrict__ W3t, const bf16* __restrict__ W4t,
    const bf16* __restrict__ attC, const float* __restrict__ deltaC,
    const int* __restrict__ cnt, double* __restrict__ acc)
{
  int a = blockIdx.y;
  int count = cnt[a];
  int start = blockIdx.x << 6;
  if (start >= count) return;
  __shared__ __align__(16) bf16 h1[64][136];   // L1/L3 out; 2-way banks (free)
  __shared__ __align__(16) bf16 tr[4][16][56]; // per-wave transpose chunk
  __shared__ float s_part[4];
  int wv = threadIdx.x >> 6, lane = threadIdx.x & 63;
  int q = lane >> 4, c = lane & 15;
  int r0 = wv << 4;

  // zero this wave's h1 pad cols 112..127 (read by A-frags at k=96..127)
  for (int i = lane; i < 16 * 16; i += 64)
    h1[r0 + (i >> 4)][112 + (i & 15)] = (bf16)0.0f;

  const bf16* W1a = W1t + a * 112 * 32;
  const bf16* W2a = W2t + a * 400 * 128;
  const bf16* W3a = W3t + a * 112 * 416;
  const bf16* W4a = W4t + a * 16 * 128;

  // ---- L1: 6(+bias)->100 ----
  bf16x8 aAtt;
#pragma unroll
  for (int i = 0; i < 8; ++i) aAtt[i] = (bf16)0.0f;
  {
    int slot = start + r0 + c;
    if (q == 0 && slot < count)
      aAtt = *(const bf16x8*)(attC + ((size_t)a * B_ROWS + slot) * 8);
  }
#pragma unroll
  for (int nt = 0; nt < 7; ++nt) {
    bf16x8 b = *(const bf16x8*)(W1a + (nt * 16 + c) * 32 + q * 8);
    f32x4 C = {0.f, 0.f, 0.f, 0.f};
    C = __builtin_amdgcn_mfma_f32_16x16x32_bf16(aAtt, b, C, 0, 0, 0);
    int n = nt * 16 + c;
#pragma unroll
    for (int rg = 0; rg < 4; ++rg) {
      float v = (n < 100) ? (C[rg] > 0.f ? C[rg] : 0.f)
                          : (n == 100 ? 1.0f : 0.0f);
      h1[r0 + q * 4 + rg][n] = (bf16)v;
    }
  }
  __builtin_amdgcn_sched_barrier(0);

  // ---- L2+L3 fused: per 32-col chunk of h2, produce->transpose->consume ----
  bf16x8 A2[4];
#pragma unroll
  for (int t = 0; t < 4; ++t)
    A2[t] = *(const bf16x8*)&h1[r0 + c][t * 32 + q * 8];
  f32x4 C3[7];
#pragma unroll
  for (int i = 0; i < 7; ++i) C3[i] = (f32x4){0.f, 0.f, 0.f, 0.f};

#pragma unroll 1
  for (int t = 0; t < 13; ++t) {
#pragma unroll
    for (int half = 0; half < 2; ++half) {
      int nt = 2 * t + half;            // L2 n-tile, 0..25
      float vals[4];
      if (nt < 25) {
        f32x4 C = {0.f, 0.f, 0.f, 0.f};
#pragma unroll
        for (int tt = 0; tt < 4; ++tt) {
          bf16x8 b = *(const bf16x8*)(W2a + (nt * 16 + c) * 128 + tt * 32 + q * 8);
          C = __builtin_amdgcn_mfma_f32_16x16x32_bf16(A2[tt], b, C, 0, 0, 0);
        }
#pragma unroll
        for (int rg = 0; rg < 4; ++rg) vals[rg] = C[rg] > 0.f ? C[rg] : 0.f;
      } else {
        int n = nt * 16 + c;            // 400..415: bias marker row
#pragma unroll
        for (int rg = 0; rg < 4; ++rg) vals[rg] = (n == 400) ? 1.0f : 0.0f;
      }
#pragma unroll
      for (int rg = 0; rg < 4; ++rg)
        tr[wv][q * 4 + rg][half * 16 + c] = (bf16)vals[rg];
    }
    __builtin_amdgcn_sched_barrier(0);  // pin tr writes before tr read
    bf16x8 A3 = *(const bf16x8*)&tr[wv][c][q * 8];
#pragma unroll
    for (int nt3 = 0; nt3 < 7; ++nt3) {
      bf16x8 b = *(const bf16x8*)(W3a + (nt3 * 16 + c) * 416 + t * 32 + q * 8);
      C3[nt3] = __builtin_amdgcn_mfma_f32_16x16x32_bf16(A3, b, C3[nt3], 0, 0, 0);
    }
    __builtin_amdgcn_sched_barrier(0);  // pin tr read before next-iter writes
  }

  // ---- L3 epilogue -> h1 ----
#pragma unroll
  for (int nt3 = 0; nt3 < 7; ++nt3) {
    int n = nt3 * 16 + c;
#pragma unroll
    for (int rg = 0; rg < 4; ++rg) {
      float v = (n < 100) ? (C3[nt3][rg] > 0.f ? C3[nt3][rg] : 0.f)
                          : (n == 100 ? 1.0f : 0.0f);
      h1[r0 + q * 4 + rg][n] = (bf16)v;
    }
  }
  __builtin_amdgcn_sched_barrier(0);

  // ---- L4: 100(+bias)->6 + MSE ----
  f32x4 C4 = {0.f, 0.f, 0.f, 0.f};
#pragma unroll
  for (int tt = 0; tt < 4; ++tt) {
    bf16x8 A4 = *(const bf16x8*)&h1[r0 + c][tt * 32 + q * 8];
    bf16x8 b = *(const bf16x8*)(W4a + c * 128 + tt * 32 + q * 8);
    C4 = __builtin_amdgcn_mfma_f32_16x16x32_bf16(A4, b, C4, 0, 0, 0);
  }
  float sq = 0.f;
  if (c < 6) {
#pragma unroll
    for (int rg = 0; rg < 4; ++rg) {
      int slot = start + r0 + q * 4 + rg;
      if (slot < count) {
        float d = deltaC[((size_t)a * B_ROWS + slot) * 6 + c];
        float e = C4[rg] - d;
        sq += e * e;
      }
    }
  }
#pragma unroll
  for (int off = 32; off; off >>= 1) sq += __shfl_xor(sq, off);
  if (lane == 0) s_part[wv] = sq;
  __syncthreads();
  if (threadIdx.x == 0) {
    float tot = s_part[0] + s_part[1] + s_part[2] + s_part[3];
    atomicAdd(acc, (double)tot);
  }
}

__global__ void k_final(const double* __restrict__ acc, float* __restrict__ out)
{
  out[0] = (float)(acc[0] / (double)(B_ROWS * 6));
}

extern "C" void kernel_launch(void* const* d_in, const int* in_sizes, int n_in,
                              void* d_out, int out_size, void* d_ws, size_t ws_size,
                              hipStream_t stream)
{
  const float* x  = (const float*)d_in[0];
  const float* xn = (const float*)d_in[1];
  const int*  act = (const int*)d_in[2];
  const float* W1 = (const float*)d_in[3];
  const float* b1 = (const float*)d_in[4];
  const float* W2 = (const float*)d_in[5];
  const float* b2 = (const float*)d_in[6];
  const float* W3 = (const float*)d_in[7];
  const float* b3 = (const float*)d_in[8];
  const float* W4 = (const float*)d_in[9];
  const float* b4 = (const float*)d_in[10];

  char* ws = (char*)d_ws;
  bf16*   W1t    = (bf16*)(ws + OFF_W1T);
  bf16*   W2t    = (bf16*)(ws + OFF_W2T);
  bf16*   W3t    = (bf16*)(ws + OFF_W3T);
  bf16*   W4t    = (bf16*)(ws + OFF_W4T);
  int*    cnt    = (int*)(ws + OFF_CNT);
  double* acc    = (double*)(ws + OFF_ACC);
  int*    ptrArr = (int*)(ws + OFF_PTR);
  bf16*   attC   = (bf16*)(ws + OFF_ATTC);
  float*  deltaC = (float*)(ws + OFF_DELTA);

  k_wprep<<<dim3(600), dim3(256), 0, stream>>>(W1, b1, W2, b2, W3, b3, W4, b4,
                                               W1t, W2t, W3t, W4t, cnt, acc, ptrArr);
  k_scan<<<dim3(SCAN_BLOCKS), dim3(256), 0, stream>>>(x, ptrArr);
  k_gather2<<<dim3(B_ROWS / 256), dim3(256), 0, stream>>>(x, xn, act, ptrArr,
                                                          attC, deltaC, cnt);
  k_mlp<<<dim3(B_ROWS / 64, 3), dim3(256), 0, stream>>>(W1t, W2t, W3t, W4t,
                                                        attC, deltaC, cnt, acc);
  k_final<<<dim3(1), dim3(1), 0, stream>>>(acc, (float*)d_out);
}

// Round 3
// 333.092 us; speedup vs baseline: 1.1401x; 1.0123x over previous
//
#include <hip/hip_runtime.h>
#include <hip/hip_bf16.h>

#define B_ROWS 65536
#define XD 362

typedef __bf16 bf16;
typedef __attribute__((ext_vector_type(8))) __bf16 bf16x8;
typedef __attribute__((ext_vector_type(4))) float f32x4;
typedef __attribute__((ext_vector_type(2))) float f32x2;

// ---- workspace layout (bytes) ----
#define OFF_W1T   0u          // [3][112][32] bf16
#define OFF_W2T   21504u      // [3][400][128] bf16
#define OFF_W3T   328704u     // [3][112][416] bf16
#define OFF_W4T   608256u     // [3][16][128] bf16
#define OFF_CNT   620544u     // int[3]
#define OFF_PTR   621056u     // int[65536]
#define OFF_ATTC  883200u     // [3][65536][8] bf16
#define OFF_DELTA 4028928u    // [3][65536][6] f32
#define OFF_PART  8747520u    // float[3072] per-block partial sums

#define MLP_BX 1024           // k_mlp grid.x

__global__ __launch_bounds__(256) void k_wprep(
    const float* __restrict__ W1, const float* __restrict__ b1,
    const float* __restrict__ W2, const float* __restrict__ b2,
    const float* __restrict__ W3, const float* __restrict__ b3,
    const float* __restrict__ W4, const float* __restrict__ b4,
    bf16* __restrict__ W1t, bf16* __restrict__ W2t,
    bf16* __restrict__ W3t, bf16* __restrict__ W4t,
    int* __restrict__ cnt, int* __restrict__ ptrArr)
{
  int i = blockIdx.x * 256 + threadIdx.x;
  if (i == 0) { cnt[0] = 0; cnt[1] = 0; cnt[2] = 0; }
  if (i < B_ROWS) ptrArr[i] = 0x7FFFFFFF;
  if (i < 3*400*128) {               // W2t [n=400][k=128]
    int k = i & 127; int rn = i >> 7; int n = rn % 400; int a = rn / 400;
    float v = 0.f;
    if (k < 100) v = W2[(a*100 + k)*400 + n];
    else if (k == 100) v = b2[a*400 + n];
    W2t[i] = (bf16)v;
  }
  if (i < 3*112*416) {               // W3t [n=112][k=416]
    int k = i % 416; int rn = i / 416; int n = rn % 112; int a = rn / 112;
    float v = 0.f;
    if (n < 100) {
      if (k < 400) v = W3[(a*400 + k)*100 + n];
      else if (k == 400) v = b3[a*100 + n];
    }
    W3t[i] = (bf16)v;
  }
  if (i < 3*112*32) {                // W1t [n=112][k=32]
    int k = i & 31; int rn = i >> 5; int n = rn % 112; int a = rn / 112;
    float v = 0.f;
    if (n < 100) {
      if (k < 6) v = W1[(a*6 + k)*100 + n];
      else if (k == 6) v = b1[a*100 + n];
    }
    W1t[i] = (bf16)v;
  }
  if (i < 3*16*128) {                // W4t [n=16][k=128]
    int k = i & 127; int rn = i >> 7; int n = rn & 15; int a = rn >> 4;
    float v = 0.f;
    if (n < 6) {
      if (k < 100) v = W4[(a*100 + k)*6 + n];
      else if (k == 100) v = b4[a*6 + n];
    }
    W4t[i] = (bf16)v;
  }
}

// Flat vectorized sentinel scan: float4 per thread-iter, rare atomicMin on hit.
#define SCAN_BLOCKS 2896   // 2896*256*8 float4 == 65536*362/4 exactly
__global__ __launch_bounds__(256) void k_scan(
    const float* __restrict__ x, int* __restrict__ ptrArr)
{
  int gid = blockIdx.x * 256 + threadIdx.x;
  const float4* x4 = (const float4*)x;
  const int total4 = B_ROWS * XD / 4;
#pragma unroll 2
  for (int i = gid; i < total4; i += SCAN_BLOCKS * 256) {
    float4 v = x4[i];
    if (v.x == 10.0f || v.y == 10.0f || v.z == 10.0f || v.w == 10.0f) {
      int flat = i * 4;
      if (v.x == 10.0f) atomicMin(&ptrArr[(flat    ) / XD], (flat    ) % XD);
      if (v.y == 10.0f) atomicMin(&ptrArr[(flat + 1) / XD], (flat + 1) % XD);
      if (v.z == 10.0f) atomicMin(&ptrArr[(flat + 2) / XD], (flat + 2) % XD);
      if (v.w == 10.0f) atomicMin(&ptrArr[(flat + 3) / XD], (flat + 3) % XD);
    }
  }
}

// One thread per row: gather 6 cells from x/xn, per-wave ballot compaction
// into action-sorted arrays (3 native int atomics per wave).
__global__ __launch_bounds__(256) void k_gather2(
    const float* __restrict__ x, const float* __restrict__ xn,
    const int* __restrict__ act, const int* __restrict__ ptrArr,
    bf16* __restrict__ attC, float* __restrict__ deltaC, int* __restrict__ cnt)
{
  int row = blockIdx.x * 256 + threadIdx.x;
  int lane = threadIdx.x & 63;
  int p = ptrArr[row];
  if (p < 20 || p > 342) p = 20;   // reference guarantees 20..342
  const float* xr = x  + (size_t)row * XD;
  const float* nr = xn + (size_t)row * XD;
  int cells[6] = {0, p, p - 19, p + 19, p - 1, p + 1};
  float av[6], dv[6];
#pragma unroll
  for (int i = 0; i < 6; ++i) {
    av[i] = xr[cells[i]];
    dv[i] = nr[cells[i]] - av[i];
  }
  int a = act[row];
  unsigned long long m0 = __ballot(a == 0);
  unsigned long long m1 = __ballot(a == 1);
  unsigned long long m2 = __ballot(a == 2);
  int b0 = 0, b1 = 0, b2 = 0;
  if (lane == 0) {
    b0 = atomicAdd(&cnt[0], (int)__popcll(m0));
    b1 = atomicAdd(&cnt[1], (int)__popcll(m1));
    b2 = atomicAdd(&cnt[2], (int)__popcll(m2));
  }
  b0 = __shfl(b0, 0); b1 = __shfl(b1, 0); b2 = __shfl(b2, 0);
  unsigned long long lt = (1ull << lane) - 1ull;
  unsigned long long ma = (a == 0) ? m0 : (a == 1) ? m1 : m2;
  int base            = (a == 0) ? b0 : (a == 1) ? b1 : b2;
  int slot = base + (int)__popcll(ma & lt);
  size_t rb = (size_t)a * B_ROWS + slot;
  bf16x8 av8;
#pragma unroll
  for (int i = 0; i < 6; ++i) av8[i] = (bf16)av[i];
  av8[6] = (bf16)1.0f;   // bias marker
  av8[7] = (bf16)0.0f;
  *(bf16x8*)(attC + rb * 8) = av8;
  f32x2 d01 = {dv[0], dv[1]}, d23 = {dv[2], dv[3]}, d45 = {dv[4], dv[5]};
  *(f32x2*)(deltaC + rb * 6)     = d01;
  *(f32x2*)(deltaC + rb * 6 + 2) = d23;
  *(f32x2*)(deltaC + rb * 6 + 4) = d45;
}

// 64 rows/block, 4 waves x one 16-row m-tile. L2->L3 fused through a tiny
// per-wave LDS transpose chunk. Per-block partial MSE -> workspace array
// (NO fp atomics: HIP fp atomicAdd is a CAS loop; 1026-way contention on one
// address was ~80 us of serialized tail in round 2).
__global__ __launch_bounds__(256) void k_mlp(
    const bf16* __restrict__ W1t, const bf16* __restrict__ W2t,
    const bf16* __restrict__ W3t, const bf16* __restrict__ W4t,
    const bf16* __restrict__ attC, const float* __restrict__ deltaC,
    const int* __restrict__ cnt, float* __restrict__ partial)
{
  int a = blockIdx.y;
  int count = cnt[a];
  int start = blockIdx.x << 6;
  int pslot = a * MLP_BX + blockIdx.x;
  if (start >= count) {
    if (threadIdx.x == 0) partial[pslot] = 0.0f;
    return;
  }
  __shared__ __align__(16) bf16 h1[64][136];   // L1/L3 out; 2-way banks (free)
  __shared__ __align__(16) bf16 tr[4][16][56]; // per-wave transpose chunk
  __shared__ float s_part[4];
  int wv = threadIdx.x >> 6, lane = threadIdx.x & 63;
  int q = lane >> 4, c = lane & 15;
  int r0 = wv << 4;

  // zero this wave's h1 pad cols 112..127 (read by A-frags at k=96..127)
  for (int i = lane; i < 16 * 16; i += 64)
    h1[r0 + (i >> 4)][112 + (i & 15)] = (bf16)0.0f;

  const bf16* W1a = W1t + a * 112 * 32;
  const bf16* W2a = W2t + a * 400 * 128;
  const bf16* W3a = W3t + a * 112 * 416;
  const bf16* W4a = W4t + a * 16 * 128;

  // ---- L1: 6(+bias)->100 ----
  bf16x8 aAtt;
#pragma unroll
  for (int i = 0; i < 8; ++i) aAtt[i] = (bf16)0.0f;
  {
    int slot = start + r0 + c;
    if (q == 0 && slot < count)
      aAtt = *(const bf16x8*)(attC + ((size_t)a * B_ROWS + slot) * 8);
  }
#pragma unroll
  for (int nt = 0; nt < 7; ++nt) {
    bf16x8 b = *(const bf16x8*)(W1a + (nt * 16 + c) * 32 + q * 8);
    f32x4 C = {0.f, 0.f, 0.f, 0.f};
    C = __builtin_amdgcn_mfma_f32_16x16x32_bf16(aAtt, b, C, 0, 0, 0);
    int n = nt * 16 + c;
#pragma unroll
    for (int rg = 0; rg < 4; ++rg) {
      float v = (n < 100) ? (C[rg] > 0.f ? C[rg] : 0.f)
                          : (n == 100 ? 1.0f : 0.0f);
      h1[r0 + q * 4 + rg][n] = (bf16)v;
    }
  }
  __builtin_amdgcn_sched_barrier(0);

  // ---- L2+L3 fused: per 32-col chunk of h2, produce->transpose->consume ----
  bf16x8 A2[4];
#pragma unroll
  for (int t = 0; t < 4; ++t)
    A2[t] = *(const bf16x8*)&h1[r0 + c][t * 32 + q * 8];
  f32x4 C3[7];
#pragma unroll
  for (int i = 0; i < 7; ++i) C3[i] = (f32x4){0.f, 0.f, 0.f, 0.f};

#pragma unroll 1
  for (int t = 0; t < 13; ++t) {
#pragma unroll
    for (int half = 0; half < 2; ++half) {
      int nt = 2 * t + half;            // L2 n-tile, 0..25
      float vals[4];
      if (nt < 25) {
        f32x4 C = {0.f, 0.f, 0.f, 0.f};
#pragma unroll
        for (int tt = 0; tt < 4; ++tt) {
          bf16x8 b = *(const bf16x8*)(W2a + (nt * 16 + c) * 128 + tt * 32 + q * 8);
          C = __builtin_amdgcn_mfma_f32_16x16x32_bf16(A2[tt], b, C, 0, 0, 0);
        }
#pragma unroll
        for (int rg = 0; rg < 4; ++rg) vals[rg] = C[rg] > 0.f ? C[rg] : 0.f;
      } else {
        int n = nt * 16 + c;            // 400..415: bias marker row
#pragma unroll
        for (int rg = 0; rg < 4; ++rg) vals[rg] = (n == 400) ? 1.0f : 0.0f;
      }
#pragma unroll
      for (int rg = 0; rg < 4; ++rg)
        tr[wv][q * 4 + rg][half * 16 + c] = (bf16)vals[rg];
    }
    __builtin_amdgcn_sched_barrier(0);  // pin tr writes before tr read
    bf16x8 A3 = *(const bf16x8*)&tr[wv][c][q * 8];
#pragma unroll
    for (int nt3 = 0; nt3 < 7; ++nt3) {
      bf16x8 b = *(const bf16x8*)(W3a + (nt3 * 16 + c) * 416 + t * 32 + q * 8);
      C3[nt3] = __builtin_amdgcn_mfma_f32_16x16x32_bf16(A3, b, C3[nt3], 0, 0, 0);
    }
    __builtin_amdgcn_sched_barrier(0);  // pin tr read before next-iter writes
  }

  // ---- L3 epilogue -> h1 ----
#pragma unroll
  for (int nt3 = 0; nt3 < 7; ++nt3) {
    int n = nt3 * 16 + c;
#pragma unroll
    for (int rg = 0; rg < 4; ++rg) {
      float v = (n < 100) ? (C3[nt3][rg] > 0.f ? C3[nt3][rg] : 0.f)
                          : (n == 100 ? 1.0f : 0.0f);
      h1[r0 + q * 4 + rg][n] = (bf16)v;
    }
  }
  __builtin_amdgcn_sched_barrier(0);

  // ---- L4: 100(+bias)->6 + MSE ----
  f32x4 C4 = {0.f, 0.f, 0.f, 0.f};
#pragma unroll
  for (int tt = 0; tt < 4; ++tt) {
    bf16x8 A4 = *(const bf16x8*)&h1[r0 + c][tt * 32 + q * 8];
    bf16x8 b = *(const bf16x8*)(W4a + c * 128 + tt * 32 + q * 8);
    C4 = __builtin_amdgcn_mfma_f32_16x16x32_bf16(A4, b, C4, 0, 0, 0);
  }
  float sq = 0.f;
  if (c < 6) {
#pragma unroll
    for (int rg = 0; rg < 4; ++rg) {
      int slot = start + r0 + q * 4 + rg;
      if (slot < count) {
        float d = deltaC[((size_t)a * B_ROWS + slot) * 6 + c];
        float e = C4[rg] - d;
        sq += e * e;
      }
    }
  }
#pragma unroll
  for (int off = 32; off; off >>= 1) sq += __shfl_xor(sq, off);
  if (lane == 0) s_part[wv] = sq;
  __syncthreads();
  if (threadIdx.x == 0)
    partial[pslot] = s_part[0] + s_part[1] + s_part[2] + s_part[3];
}

// One-block tree reduction over 3072 per-block partials.
__global__ __launch_bounds__(256) void k_final(
    const float* __restrict__ partial, float* __restrict__ out)
{
  __shared__ float s[4];
  int t = threadIdx.x, lane = t & 63, wv = t >> 6;
  float sum = 0.f;
  for (int i = t; i < 3 * MLP_BX; i += 256) sum += partial[i];
#pragma unroll
  for (int off = 32; off; off >>= 1) sum += __shfl_xor(sum, off);
  if (lane == 0) s[wv] = sum;
  __syncthreads();
  if (t == 0) {
    double tot = (double)s[0] + s[1] + s[2] + s[3];
    out[0] = (float)(tot / (double)(B_ROWS * 6));
  }
}

extern "C" void kernel_launch(void* const* d_in, const int* in_sizes, int n_in,
                              void* d_out, int out_size, void* d_ws, size_t ws_size,
                              hipStream_t stream)
{
  const float* x  = (const float*)d_in[0];
  const float* xn = (const float*)d_in[1];
  const int*  act = (const int*)d_in[2];
  const float* W1 = (const float*)d_in[3];
  const float* b1 = (const float*)d_in[4];
  const float* W2 = (const float*)d_in[5];
  const float* b2 = (const float*)d_in[6];
  const float* W3 = (const float*)d_in[7];
  const float* b3 = (const float*)d_in[8];
  const float* W4 = (const float*)d_in[9];
  const float* b4 = (const float*)d_in[10];

  char* ws = (char*)d_ws;
  bf16*   W1t    = (bf16*)(ws + OFF_W1T);
  bf16*   W2t    = (bf16*)(ws + OFF_W2T);
  bf16*   W3t    = (bf16*)(ws + OFF_W3T);
  bf16*   W4t    = (bf16*)(ws + OFF_W4T);
  int*    cnt    = (int*)(ws + OFF_CNT);
  int*    ptrArr = (int*)(ws + OFF_PTR);
  bf16*   attC   = (bf16*)(ws + OFF_ATTC);
  float*  deltaC = (float*)(ws + OFF_DELTA);
  float*  part   = (float*)(ws + OFF_PART);

  k_wprep<<<dim3(600), dim3(256), 0, stream>>>(W1, b1, W2, b2, W3, b3, W4, b4,
                                               W1t, W2t, W3t, W4t, cnt, ptrArr);
  k_scan<<<dim3(SCAN_BLOCKS), dim3(256), 0, stream>>>(x, ptrArr);
  k_gather2<<<dim3(B_ROWS / 256), dim3(256), 0, stream>>>(x, xn, act, ptrArr,
                                                          attC, deltaC, cnt);
  k_mlp<<<dim3(MLP_BX, 3), dim3(256), 0, stream>>>(W1t, W2t, W3t, W4t,
                                                   attC, deltaC, cnt, part);
  k_final<<<dim3(1), dim3(256), 0, stream>>>(part, (float*)d_out);
}

// Round 4
// 298.452 us; speedup vs baseline: 1.2724x; 1.1161x over previous
//
#include <hip/hip_runtime.h>
#include <hip/hip_bf16.h>

#define B_ROWS 65536
#define XD 362

typedef __bf16 bf16;
typedef __attribute__((ext_vector_type(8))) __bf16 bf16x8;
typedef __attribute__((ext_vector_type(4))) float f32x4;
typedef __attribute__((ext_vector_type(2))) float f32x2;

#define MFMA16(A, Bf, C) __builtin_amdgcn_mfma_f32_16x16x32_bf16(A, Bf, C, 0, 0, 0)
// Order LDS write->read within a wave: wavefront fence (IR-level, lowers to
// nothing) + sched_barrier letting VALU/SALU/MFMA/VMEM cross but NOT DS.
#define ORDER() do { __builtin_amdgcn_fence(__ATOMIC_ACQ_REL, "wavefront"); \
                     __builtin_amdgcn_sched_barrier(0x7F); } while (0)

// ---- workspace layout (bytes) ----
#define OFF_W1T   0u          // [3][112][32] bf16
#define OFF_W2T   21504u      // [3][400][128] bf16
#define OFF_W3T   328704u     // [3][112][416] bf16
#define OFF_W4T   608256u     // [3][16][128] bf16
#define OFF_CNT   620544u     // int[3]
#define OFF_PTR   621056u     // int[65536]
#define OFF_ATTC  883200u     // [3][65536][8] bf16
#define OFF_DELTA 4028928u    // [3][65536][6] f32
#define OFF_PART  8747520u    // float[1536] per-block partial sums

#define MLP_BX 512            // k_mlp grid.x (512*128 rows covers any count)
#define WPREP_BLOCKS 600
#define SCAN_BLOCKS 2896      // 2896*256*8 float4 == 65536*362/4 exactly

// Fused: weight transpose/pack (blocks 0..599) + flat sentinel scan (rest).
// Scan uses PLAIN stores (sentinel unique per row -> exactly one write/row,
// no init pass needed).
__global__ __launch_bounds__(256) void k_prep(
    const float* __restrict__ W1, const float* __restrict__ b1,
    const float* __restrict__ W2, const float* __restrict__ b2,
    const float* __restrict__ W3, const float* __restrict__ b3,
    const float* __restrict__ W4, const float* __restrict__ b4,
    const float* __restrict__ x,
    bf16* __restrict__ W1t, bf16* __restrict__ W2t,
    bf16* __restrict__ W3t, bf16* __restrict__ W4t,
    int* __restrict__ cnt, int* __restrict__ ptrArr)
{
  int bx = blockIdx.x;
  if (bx >= WPREP_BLOCKS) {
    int gid = (bx - WPREP_BLOCKS) * 256 + threadIdx.x;
    const float4* x4 = (const float4*)x;
#pragma unroll
    for (int u = 0; u < 8; ++u) {
      int i = gid + u * (SCAN_BLOCKS * 256);   // exact coverage, no bounds chk
      float4 v = x4[i];
      if (v.x == 10.0f || v.y == 10.0f || v.z == 10.0f || v.w == 10.0f) {
        int flat = i * 4;
        if (v.x == 10.0f) ptrArr[(flat    ) / XD] = (flat    ) % XD;
        if (v.y == 10.0f) ptrArr[(flat + 1) / XD] = (flat + 1) % XD;
        if (v.z == 10.0f) ptrArr[(flat + 2) / XD] = (flat + 2) % XD;
        if (v.w == 10.0f) ptrArr[(flat + 3) / XD] = (flat + 3) % XD;
      }
    }
    return;
  }
  int i = bx * 256 + threadIdx.x;
  if (i == 0) { cnt[0] = 0; cnt[1] = 0; cnt[2] = 0; }
  if (i < 3*400*128) {               // W2t [n=400][k=128]
    int k = i & 127; int rn = i >> 7; int n = rn % 400; int a = rn / 400;
    float v = 0.f;
    if (k < 100) v = W2[(a*100 + k)*400 + n];
    else if (k == 100) v = b2[a*400 + n];
    W2t[i] = (bf16)v;
  }
  if (i < 3*112*416) {               // W3t [n=112][k=416]
    int k = i % 416; int rn = i / 416; int n = rn % 112; int a = rn / 112;
    float v = 0.f;
    if (n < 100) {
      if (k < 400) v = W3[(a*400 + k)*100 + n];
      else if (k == 400) v = b3[a*100 + n];
    }
    W3t[i] = (bf16)v;
  }
  if (i < 3*112*32) {                // W1t [n=112][k=32]
    int k = i & 31; int rn = i >> 5; int n = rn % 112; int a = rn / 112;
    float v = 0.f;
    if (n < 100) {
      if (k < 6) v = W1[(a*6 + k)*100 + n];
      else if (k == 6) v = b1[a*100 + n];
    }
    W1t[i] = (bf16)v;
  }
  if (i < 3*16*128) {                // W4t [n=16][k=128]
    int k = i & 127; int rn = i >> 7; int n = rn & 15; int a = rn >> 4;
    float v = 0.f;
    if (n < 6) {
      if (k < 100) v = W4[(a*100 + k)*6 + n];
      else if (k == 100) v = b4[a*6 + n];
    }
    W4t[i] = (bf16)v;
  }
}

// One thread per row: gather 6 cells from x/xn, per-wave ballot compaction
// into action-sorted arrays (3 native int atomics per wave).
__global__ __launch_bounds__(256) void k_gather2(
    const float* __restrict__ x, const float* __restrict__ xn,
    const int* __restrict__ act, const int* __restrict__ ptrArr,
    bf16* __restrict__ attC, float* __restrict__ deltaC, int* __restrict__ cnt)
{
  int row = blockIdx.x * 256 + threadIdx.x;
  int lane = threadIdx.x & 63;
  int p = ptrArr[row];
  if (p < 20 || p > 342) p = 20;   // reference guarantees 20..342
  const float* xr = x  + (size_t)row * XD;
  const float* nr = xn + (size_t)row * XD;
  int cells[6] = {0, p, p - 19, p + 19, p - 1, p + 1};
  float av[6], dv[6];
#pragma unroll
  for (int i = 0; i < 6; ++i) {
    av[i] = xr[cells[i]];
    dv[i] = nr[cells[i]] - av[i];
  }
  int a = act[row];
  unsigned long long m0 = __ballot(a == 0);
  unsigned long long m1 = __ballot(a == 1);
  unsigned long long m2 = __ballot(a == 2);
  int b0 = 0, b1 = 0, b2 = 0;
  if (lane == 0) {
    b0 = atomicAdd(&cnt[0], (int)__popcll(m0));
    b1 = atomicAdd(&cnt[1], (int)__popcll(m1));
    b2 = atomicAdd(&cnt[2], (int)__popcll(m2));
  }
  b0 = __shfl(b0, 0); b1 = __shfl(b1, 0); b2 = __shfl(b2, 0);
  unsigned long long lt = (1ull << lane) - 1ull;
  unsigned long long ma = (a == 0) ? m0 : (a == 1) ? m1 : m2;
  int base            = (a == 0) ? b0 : (a == 1) ? b1 : b2;
  int slot = base + (int)__popcll(ma & lt);
  size_t rb = (size_t)a * B_ROWS + slot;
  bf16x8 av8;
#pragma unroll
  for (int i = 0; i < 6; ++i) av8[i] = (bf16)av[i];
  av8[6] = (bf16)1.0f;   // bias marker
  av8[7] = (bf16)0.0f;
  *(bf16x8*)(attC + rb * 8) = av8;
  f32x2 d01 = {dv[0], dv[1]}, d23 = {dv[2], dv[3]}, d45 = {dv[4], dv[5]};
  *(f32x2*)(deltaC + rb * 6)     = d01;
  *(f32x2*)(deltaC + rb * 6 + 2) = d23;
  *(f32x2*)(deltaC + rb * 6 + 4) = d45;
}

// 128 rows/block: 4 waves x TWO 16-row m-tiles each. B-fragments shared
// across the 2 m-tiles (2:1 MFMA:load), L2->L3 fused through per-wave LDS
// transpose chunks. sched_barrier(0x7F) keeps DS ordered but lets weight
// loads pipeline across iterations.
__global__ __launch_bounds__(256) void k_mlp(
    const bf16* __restrict__ W1t, const bf16* __restrict__ W2t,
    const bf16* __restrict__ W3t, const bf16* __restrict__ W4t,
    const bf16* __restrict__ attC, const float* __restrict__ deltaC,
    const int* __restrict__ cnt, float* __restrict__ partial)
{
  int a = blockIdx.y;
  int count = cnt[a];
  int start = blockIdx.x << 7;
  int pslot = a * MLP_BX + blockIdx.x;
  __shared__ __align__(16) bf16 h1s[4][16][136];   // per-wave scratch
  __shared__ __align__(16) bf16 tr[4][2][16][56];  // per-wave,per-mtile chunk
  __shared__ float s_part[4];
  int wv = threadIdx.x >> 6, lane = threadIdx.x & 63;
  int q = lane >> 4, c = lane & 15;

  if (start < count) {
    const bf16* W1a = W1t + a * 112 * 32;
    const bf16* W2a = W2t + a * 400 * 128;
    const bf16* W3a = W3t + a * 112 * 416;
    const bf16* W4a = W4t + a * 16 * 128;

    // zero this wave's h1s pad cols 112..127 (read as A-frag k=96..127)
    for (int i = lane; i < 16 * 16; i += 64)
      h1s[wv][i >> 4][112 + (i & 15)] = (bf16)0.0f;

    // ---- L1: 6(+bias)->100, per m-tile, A2 frags kept in registers ----
    bf16x8 A2[2][4];
#pragma unroll
    for (int mi = 0; mi < 2; ++mi) {
      bf16x8 aAtt;
#pragma unroll
      for (int i = 0; i < 8; ++i) aAtt[i] = (bf16)0.0f;
      int slot = start + wv * 32 + mi * 16 + c;
      if (q == 0 && slot < count)
        aAtt = *(const bf16x8*)(attC + ((size_t)a * B_ROWS + slot) * 8);
#pragma unroll
      for (int nt = 0; nt < 7; ++nt) {
        bf16x8 b = *(const bf16x8*)(W1a + (nt * 16 + c) * 32 + q * 8);
        f32x4 C = {0.f, 0.f, 0.f, 0.f};
        C = MFMA16(aAtt, b, C);
        int n = nt * 16 + c;
#pragma unroll
        for (int rg = 0; rg < 4; ++rg) {
          float v = (n < 100) ? (C[rg] > 0.f ? C[rg] : 0.f)
                              : (n == 100 ? 1.0f : 0.0f);
          h1s[wv][q * 4 + rg][n] = (bf16)v;
        }
      }
      ORDER();
#pragma unroll
      for (int tt = 0; tt < 4; ++tt)
        A2[mi][tt] = *(const bf16x8*)&h1s[wv][c][tt * 32 + q * 8];
      ORDER();   // before next mi overwrites h1s
    }

    f32x4 C3[2][7];
#pragma unroll
    for (int mi = 0; mi < 2; ++mi)
#pragma unroll
      for (int i = 0; i < 7; ++i) C3[mi][i] = (f32x4){0.f, 0.f, 0.f, 0.f};

    // ---- L2+L3 fused, t = 0..11 (both n-tiles real) ----
#pragma unroll 1
    for (int t = 0; t < 12; ++t) {
      bf16x8 b2f[2][4];
#pragma unroll
      for (int half = 0; half < 2; ++half)
#pragma unroll
        for (int tt = 0; tt < 4; ++tt)
          b2f[half][tt] = *(const bf16x8*)(W2a + ((2*t + half) * 16 + c) * 128 + tt * 32 + q * 8);
#pragma unroll
      for (int mi = 0; mi < 2; ++mi)
#pragma unroll
        for (int half = 0; half < 2; ++half) {
          f32x4 C = {0.f, 0.f, 0.f, 0.f};
#pragma unroll
          for (int tt = 0; tt < 4; ++tt)
            C = MFMA16(A2[mi][tt], b2f[half][tt], C);
#pragma unroll
          for (int rg = 0; rg < 4; ++rg) {
            float v = C[rg] > 0.f ? C[rg] : 0.f;
            tr[wv][mi][q * 4 + rg][half * 16 + c] = (bf16)v;
          }
        }
      ORDER();
      bf16x8 A3a = *(const bf16x8*)&tr[wv][0][c][q * 8];
      bf16x8 A3b = *(const bf16x8*)&tr[wv][1][c][q * 8];
#pragma unroll
      for (int nt3 = 0; nt3 < 7; ++nt3) {
        bf16x8 b = *(const bf16x8*)(W3a + (nt3 * 16 + c) * 416 + t * 32 + q * 8);
        C3[0][nt3] = MFMA16(A3a, b, C3[0][nt3]);
        C3[1][nt3] = MFMA16(A3b, b, C3[1][nt3]);
      }
      ORDER();
    }
    // ---- t = 12: n-tile 24 real, 25 = bias-marker row ----
    {
      const int t = 12;
      bf16x8 b2f[4];
#pragma unroll
      for (int tt = 0; tt < 4; ++tt)
        b2f[tt] = *(const bf16x8*)(W2a + (24 * 16 + c) * 128 + tt * 32 + q * 8);
#pragma unroll
      for (int mi = 0; mi < 2; ++mi) {
        f32x4 C = {0.f, 0.f, 0.f, 0.f};
#pragma unroll
        for (int tt = 0; tt < 4; ++tt)
          C = MFMA16(A2[mi][tt], b2f[tt], C);
#pragma unroll
        for (int rg = 0; rg < 4; ++rg) {
          float v = C[rg] > 0.f ? C[rg] : 0.f;
          tr[wv][mi][q * 4 + rg][c]      = (bf16)v;
          tr[wv][mi][q * 4 + rg][16 + c] = (bf16)((c == 0) ? 1.0f : 0.0f);
        }
      }
      ORDER();
      bf16x8 A3a = *(const bf16x8*)&tr[wv][0][c][q * 8];
      bf16x8 A3b = *(const bf16x8*)&tr[wv][1][c][q * 8];
#pragma unroll
      for (int nt3 = 0; nt3 < 7; ++nt3) {
        bf16x8 b = *(const bf16x8*)(W3a + (nt3 * 16 + c) * 416 + t * 32 + q * 8);
        C3[0][nt3] = MFMA16(A3a, b, C3[0][nt3]);
        C3[1][nt3] = MFMA16(A3b, b, C3[1][nt3]);
      }
      ORDER();
    }

    // ---- L4: 100(+bias)->6 + MSE, per m-tile (h1s serial reuse) ----
    bf16x8 b4f[4];
#pragma unroll
    for (int tt = 0; tt < 4; ++tt)
      b4f[tt] = *(const bf16x8*)(W4a + c * 128 + tt * 32 + q * 8);
    float sq = 0.f;
#pragma unroll
    for (int mi = 0; mi < 2; ++mi) {
#pragma unroll
      for (int nt3 = 0; nt3 < 7; ++nt3) {
        int n = nt3 * 16 + c;
#pragma unroll
        for (int rg = 0; rg < 4; ++rg) {
          float v = (n < 100) ? (C3[mi][nt3][rg] > 0.f ? C3[mi][nt3][rg] : 0.f)
                              : (n == 100 ? 1.0f : 0.0f);
          h1s[wv][q * 4 + rg][n] = (bf16)v;
        }
      }
      ORDER();
      f32x4 C4 = {0.f, 0.f, 0.f, 0.f};
#pragma unroll
      for (int tt = 0; tt < 4; ++tt) {
        bf16x8 A4 = *(const bf16x8*)&h1s[wv][c][tt * 32 + q * 8];
        C4 = MFMA16(A4, b4f[tt], C4);
      }
      ORDER();   // before next mi overwrites h1s
      if (c < 6) {
#pragma unroll
        for (int rg = 0; rg < 4; ++rg) {
          int slot = start + wv * 32 + mi * 16 + q * 4 + rg;
          if (slot < count) {
            float d = deltaC[((size_t)a * B_ROWS + slot) * 6 + c];
            float e = C4[rg] - d;
            sq += e * e;
          }
        }
      }
    }
#pragma unroll
    for (int off = 32; off; off >>= 1) sq += __shfl_xor(sq, off);
    if (lane == 0) s_part[wv] = sq;
  } else {
    if (lane == 0) s_part[wv] = 0.f;
  }
  __syncthreads();
  if (threadIdx.x == 0)
    partial[pslot] = s_part[0] + s_part[1] + s_part[2] + s_part[3];
}

// One-block tree reduction over 1536 per-block partials.
__global__ __launch_bounds__(256) void k_final(
    const float* __restrict__ partial, float* __restrict__ out)
{
  __shared__ float s[4];
  int t = threadIdx.x, lane = t & 63, wv = t >> 6;
  float sum = 0.f;
  for (int i = t; i < 3 * MLP_BX; i += 256) sum += partial[i];
#pragma unroll
  for (int off = 32; off; off >>= 1) sum += __shfl_xor(sum, off);
  if (lane == 0) s[wv] = sum;
  __syncthreads();
  if (t == 0) {
    double tot = (double)s[0] + s[1] + s[2] + s[3];
    out[0] = (float)(tot / (double)(B_ROWS * 6));
  }
}

extern "C" void kernel_launch(void* const* d_in, const int* in_sizes, int n_in,
                              void* d_out, int out_size, void* d_ws, size_t ws_size,
                              hipStream_t stream)
{
  const float* x  = (const float*)d_in[0];
  const float* xn = (const float*)d_in[1];
  const int*  act = (const int*)d_in[2];
  const float* W1 = (const float*)d_in[3];
  const float* b1 = (const float*)d_in[4];
  const float* W2 = (const float*)d_in[5];
  const float* b2 = (const float*)d_in[6];
  const float* W3 = (const float*)d_in[7];
  const float* b3 = (const float*)d_in[8];
  const float* W4 = (const float*)d_in[9];
  const float* b4 = (const float*)d_in[10];

  char* ws = (char*)d_ws;
  bf16*   W1t    = (bf16*)(ws + OFF_W1T);
  bf16*   W2t    = (bf16*)(ws + OFF_W2T);
  bf16*   W3t    = (bf16*)(ws + OFF_W3T);
  bf16*   W4t    = (bf16*)(ws + OFF_W4T);
  int*    cnt    = (int*)(ws + OFF_CNT);
  int*    ptrArr = (int*)(ws + OFF_PTR);
  bf16*   attC   = (bf16*)(ws + OFF_ATTC);
  float*  deltaC = (float*)(ws + OFF_DELTA);
  float*  part   = (float*)(ws + OFF_PART);

  k_prep<<<dim3(WPREP_BLOCKS + SCAN_BLOCKS), dim3(256), 0, stream>>>(
      W1, b1, W2, b2, W3, b3, W4, b4, x, W1t, W2t, W3t, W4t, cnt, ptrArr);
  k_gather2<<<dim3(B_ROWS / 256), dim3(256), 0, stream>>>(x, xn, act, ptrArr,
                                                          attC, deltaC, cnt);
  k_mlp<<<dim3(MLP_BX, 3), dim3(256), 0, stream>>>(W1t, W2t, W3t, W4t,
                                                   attC, deltaC, cnt, part);
  k_final<<<dim3(1), dim3(256), 0, stream>>>(part, (float*)d_out);
}

// Round 5
// 296.810 us; speedup vs baseline: 1.2794x; 1.0055x over previous
//
#include <hip/hip_runtime.h>
#include <hip/hip_bf16.h>

#define B_ROWS 65536
#define XD 362

typedef __bf16 bf16;
typedef __attribute__((ext_vector_type(8))) __bf16 bf16x8;
typedef __attribute__((ext_vector_type(4))) float f32x4;
typedef __attribute__((ext_vector_type(2))) float f32x2;

#define MFMA16(A, Bf, C) __builtin_amdgcn_mfma_f32_16x16x32_bf16(A, Bf, C, 0, 0, 0)
// Keep DS ops ordered at this point (compiler-level); VALU/SALU/MFMA/VMEM may
// cross freely so weight loads can pipeline. HW executes a wave's DS ops in
// order, so no fence/waitcnt is needed for the LDS round-trip.
#define ORDER() __builtin_amdgcn_sched_barrier(0x7F)

// ---- workspace layout (bytes) ----
#define OFF_W1T   0u          // [3][112][32] bf16
#define OFF_W2T   21504u      // [3][400][128] bf16
#define OFF_W3T   328704u     // [3][112][416] bf16
#define OFF_W4T   608256u     // [3][16][128] bf16
#define OFF_CNT   620544u     // int[3]
#define OFF_PTR   621056u     // int[65536]
#define OFF_ATTC  883200u     // [3][65536][8] bf16
#define OFF_DELTA 4028928u    // [3][65536][6] f32
#define OFF_PART  8747520u    // float[1536] per-block partial sums

#define MLP_BX 512            // k_mlp grid.x (512*128 rows covers any count)
#define WPREP_BLOCKS 600
#define SCAN_BLOCKS 2896      // 2896*256*8 float4 == 65536*362/4 exactly

// Fused: weight transpose/pack (blocks 0..599) + flat sentinel scan (rest).
__global__ __launch_bounds__(256) void k_prep(
    const float* __restrict__ W1, const float* __restrict__ b1,
    const float* __restrict__ W2, const float* __restrict__ b2,
    const float* __restrict__ W3, const float* __restrict__ b3,
    const float* __restrict__ W4, const float* __restrict__ b4,
    const float* __restrict__ x,
    bf16* __restrict__ W1t, bf16* __restrict__ W2t,
    bf16* __restrict__ W3t, bf16* __restrict__ W4t,
    int* __restrict__ cnt, int* __restrict__ ptrArr)
{
  int bx = blockIdx.x;
  if (bx >= WPREP_BLOCKS) {
    int gid = (bx - WPREP_BLOCKS) * 256 + threadIdx.x;
    const float4* x4 = (const float4*)x;
#pragma unroll
    for (int u = 0; u < 8; ++u) {
      int i = gid + u * (SCAN_BLOCKS * 256);   // exact coverage, no bounds chk
      float4 v = x4[i];
      if (v.x == 10.0f || v.y == 10.0f || v.z == 10.0f || v.w == 10.0f) {
        int flat = i * 4;
        if (v.x == 10.0f) ptrArr[(flat    ) / XD] = (flat    ) % XD;
        if (v.y == 10.0f) ptrArr[(flat + 1) / XD] = (flat + 1) % XD;
        if (v.z == 10.0f) ptrArr[(flat + 2) / XD] = (flat + 2) % XD;
        if (v.w == 10.0f) ptrArr[(flat + 3) / XD] = (flat + 3) % XD;
      }
    }
    return;
  }
  int i = bx * 256 + threadIdx.x;
  if (i == 0) { cnt[0] = 0; cnt[1] = 0; cnt[2] = 0; }
  if (i < 3*400*128) {               // W2t [n=400][k=128]
    int k = i & 127; int rn = i >> 7; int n = rn % 400; int a = rn / 400;
    float v = 0.f;
    if (k < 100) v = W2[(a*100 + k)*400 + n];
    else if (k == 100) v = b2[a*400 + n];
    W2t[i] = (bf16)v;
  }
  if (i < 3*112*416) {               // W3t [n=112][k=416]
    int k = i % 416; int rn = i / 416; int n = rn % 112; int a = rn / 112;
    float v = 0.f;
    if (n < 100) {
      if (k < 400) v = W3[(a*400 + k)*100 + n];
      else if (k == 400) v = b3[a*100 + n];
    }
    W3t[i] = (bf16)v;
  }
  if (i < 3*112*32) {                // W1t [n=112][k=32]
    int k = i & 31; int rn = i >> 5; int n = rn % 112; int a = rn / 112;
    float v = 0.f;
    if (n < 100) {
      if (k < 6) v = W1[(a*6 + k)*100 + n];
      else if (k == 6) v = b1[a*100 + n];
    }
    W1t[i] = (bf16)v;
  }
  if (i < 3*16*128) {                // W4t [n=16][k=128]
    int k = i & 127; int rn = i >> 7; int n = rn & 15; int a = rn >> 4;
    float v = 0.f;
    if (n < 6) {
      if (k < 100) v = W4[(a*100 + k)*6 + n];
      else if (k == 100) v = b4[a*6 + n];
    }
    W4t[i] = (bf16)v;
  }
}

// One thread per row: gather 6 cells from x/xn, per-wave ballot compaction
// into action-sorted arrays (3 native int atomics per wave).
__global__ __launch_bounds__(256) void k_gather2(
    const float* __restrict__ x, const float* __restrict__ xn,
    const int* __restrict__ act, const int* __restrict__ ptrArr,
    bf16* __restrict__ attC, float* __restrict__ deltaC, int* __restrict__ cnt)
{
  int row = blockIdx.x * 256 + threadIdx.x;
  int lane = threadIdx.x & 63;
  int p = ptrArr[row];
  if (p < 20 || p > 342) p = 20;   // reference guarantees 20..342
  const float* xr = x  + (size_t)row * XD;
  const float* nr = xn + (size_t)row * XD;
  int cells[6] = {0, p, p - 19, p + 19, p - 1, p + 1};
  float av[6], dv[6];
#pragma unroll
  for (int i = 0; i < 6; ++i) {
    av[i] = xr[cells[i]];
    dv[i] = nr[cells[i]] - av[i];
  }
  int a = act[row];
  unsigned long long m0 = __ballot(a == 0);
  unsigned long long m1 = __ballot(a == 1);
  unsigned long long m2 = __ballot(a == 2);
  int b0 = 0, b1 = 0, b2 = 0;
  if (lane == 0) {
    b0 = atomicAdd(&cnt[0], (int)__popcll(m0));
    b1 = atomicAdd(&cnt[1], (int)__popcll(m1));
    b2 = atomicAdd(&cnt[2], (int)__popcll(m2));
  }
  b0 = __shfl(b0, 0); b1 = __shfl(b1, 0); b2 = __shfl(b2, 0);
  unsigned long long lt = (1ull << lane) - 1ull;
  unsigned long long ma = (a == 0) ? m0 : (a == 1) ? m1 : m2;
  int base            = (a == 0) ? b0 : (a == 1) ? b1 : b2;
  int slot = base + (int)__popcll(ma & lt);
  size_t rb = (size_t)a * B_ROWS + slot;
  bf16x8 av8;
#pragma unroll
  for (int i = 0; i < 6; ++i) av8[i] = (bf16)av[i];
  av8[6] = (bf16)1.0f;   // bias marker
  av8[7] = (bf16)0.0f;
  *(bf16x8*)(attC + rb * 8) = av8;
  f32x2 d01 = {dv[0], dv[1]}, d23 = {dv[2], dv[3]}, d45 = {dv[4], dv[5]};
  *(f32x2*)(deltaC + rb * 6)     = d01;
  *(f32x2*)(deltaC + rb * 6 + 2) = d23;
  *(f32x2*)(deltaC + rb * 6 + 4) = d45;
}

// 128 rows/block: 4 waves x TWO 16-row m-tiles each. B-fragments shared
// across the 2 m-tiles, L2->L3 fused through per-wave LDS transpose chunks.
// __launch_bounds__(256,2): only ~2 waves/SIMD of work exist, so let the
// allocator use up to 256 VGPRs — at VGPR=100 (round 4) the accumulators
// (88 regs) starved the loader into serial just-in-time loads.
__global__ __launch_bounds__(256, 2) void k_mlp(
    const bf16* __restrict__ W1t, const bf16* __restrict__ W2t,
    const bf16* __restrict__ W3t, const bf16* __restrict__ W4t,
    const bf16* __restrict__ attC, const float* __restrict__ deltaC,
    const int* __restrict__ cnt, float* __restrict__ partial)
{
  int a = blockIdx.y;
  int count = cnt[a];
  int start = blockIdx.x << 7;
  int pslot = a * MLP_BX + blockIdx.x;
  __shared__ __align__(16) bf16 h1s[4][16][136];   // per-wave scratch
  __shared__ __align__(16) bf16 tr[4][2][16][56];  // per-wave,per-mtile chunk
  __shared__ float s_part[4];
  int wv = threadIdx.x >> 6, lane = threadIdx.x & 63;
  int q = lane >> 4, c = lane & 15;

  if (start < count) {
    const bf16* W1a = W1t + a * 112 * 32;
    const bf16* W2a = W2t + a * 400 * 128;
    const bf16* W3a = W3t + a * 112 * 416;
    const bf16* W4a = W4t + a * 16 * 128;

    // zero this wave's h1s pad cols 112..127 (read as A-frag k=96..127)
    for (int i = lane; i < 16 * 16; i += 64)
      h1s[wv][i >> 4][112 + (i & 15)] = (bf16)0.0f;

    // ---- L1: 6(+bias)->100, per m-tile, A2 frags kept in registers ----
    bf16x8 A2[2][4];
#pragma unroll
    for (int mi = 0; mi < 2; ++mi) {
      bf16x8 aAtt;
#pragma unroll
      for (int i = 0; i < 8; ++i) aAtt[i] = (bf16)0.0f;
      int slot = start + wv * 32 + mi * 16 + c;
      if (q == 0 && slot < count)
        aAtt = *(const bf16x8*)(attC + ((size_t)a * B_ROWS + slot) * 8);
#pragma unroll
      for (int nt = 0; nt < 7; ++nt) {
        bf16x8 b = *(const bf16x8*)(W1a + (nt * 16 + c) * 32 + q * 8);
        f32x4 C = {0.f, 0.f, 0.f, 0.f};
        C = MFMA16(aAtt, b, C);
        int n = nt * 16 + c;
#pragma unroll
        for (int rg = 0; rg < 4; ++rg) {
          float v = (n < 100) ? (C[rg] > 0.f ? C[rg] : 0.f)
                              : (n == 100 ? 1.0f : 0.0f);
          h1s[wv][q * 4 + rg][n] = (bf16)v;
        }
      }
      ORDER();
#pragma unroll
      for (int tt = 0; tt < 4; ++tt)
        A2[mi][tt] = *(const bf16x8*)&h1s[wv][c][tt * 32 + q * 8];
      ORDER();   // before next mi overwrites h1s
    }

    f32x4 C3[2][7];
#pragma unroll
    for (int mi = 0; mi < 2; ++mi)
#pragma unroll
      for (int i = 0; i < 7; ++i) C3[mi][i] = (f32x4){0.f, 0.f, 0.f, 0.f};

    // ---- L2+L3 fused, t = 0..11 (both n-tiles real) ----
#pragma unroll 2
    for (int t = 0; t < 12; ++t) {
      bf16x8 b2f[2][4];
#pragma unroll
      for (int half = 0; half < 2; ++half)
#pragma unroll
        for (int tt = 0; tt < 4; ++tt)
          b2f[half][tt] = *(const bf16x8*)(W2a + ((2*t + half) * 16 + c) * 128 + tt * 32 + q * 8);
#pragma unroll
      for (int mi = 0; mi < 2; ++mi)
#pragma unroll
        for (int half = 0; half < 2; ++half) {
          f32x4 C = {0.f, 0.f, 0.f, 0.f};
#pragma unroll
          for (int tt = 0; tt < 4; ++tt)
            C = MFMA16(A2[mi][tt], b2f[half][tt], C);
#pragma unroll
          for (int rg = 0; rg < 4; ++rg) {
            float v = C[rg] > 0.f ? C[rg] : 0.f;
            tr[wv][mi][q * 4 + rg][half * 16 + c] = (bf16)v;
          }
        }
      ORDER();
      bf16x8 A3a = *(const bf16x8*)&tr[wv][0][c][q * 8];
      bf16x8 A3b = *(const bf16x8*)&tr[wv][1][c][q * 8];
#pragma unroll
      for (int nt3 = 0; nt3 < 7; ++nt3) {
        bf16x8 b = *(const bf16x8*)(W3a + (nt3 * 16 + c) * 416 + t * 32 + q * 8);
        C3[0][nt3] = MFMA16(A3a, b, C3[0][nt3]);
        C3[1][nt3] = MFMA16(A3b, b, C3[1][nt3]);
      }
      ORDER();
    }
    // ---- t = 12: n-tile 24 real, 25 = bias-marker row ----
    {
      const int t = 12;
      bf16x8 b2f[4];
#pragma unroll
      for (int tt = 0; tt < 4; ++tt)
        b2f[tt] = *(const bf16x8*)(W2a + (24 * 16 + c) * 128 + tt * 32 + q * 8);
#pragma unroll
      for (int mi = 0; mi < 2; ++mi) {
        f32x4 C = {0.f, 0.f, 0.f, 0.f};
#pragma unroll
        for (int tt = 0; tt < 4; ++tt)
          C = MFMA16(A2[mi][tt], b2f[tt], C);
#pragma unroll
        for (int rg = 0; rg < 4; ++rg) {
          float v = C[rg] > 0.f ? C[rg] : 0.f;
          tr[wv][mi][q * 4 + rg][c]      = (bf16)v;
          tr[wv][mi][q * 4 + rg][16 + c] = (bf16)((c == 0) ? 1.0f : 0.0f);
        }
      }
      ORDER();
      bf16x8 A3a = *(const bf16x8*)&tr[wv][0][c][q * 8];
      bf16x8 A3b = *(const bf16x8*)&tr[wv][1][c][q * 8];
#pragma unroll
      for (int nt3 = 0; nt3 < 7; ++nt3) {
        bf16x8 b = *(const bf16x8*)(W3a + (nt3 * 16 + c) * 416 + t * 32 + q * 8);
        C3[0][nt3] = MFMA16(A3a, b, C3[0][nt3]);
        C3[1][nt3] = MFMA16(A3b, b, C3[1][nt3]);
      }
      ORDER();
    }

    // ---- L4: 100(+bias)->6 + MSE, per m-tile (h1s serial reuse) ----
    bf16x8 b4f[4];
#pragma unroll
    for (int tt = 0; tt < 4; ++tt)
      b4f[tt] = *(const bf16x8*)(W4a + c * 128 + tt * 32 + q * 8);
    float sq = 0.f;
#pragma unroll
    for (int mi = 0; mi < 2; ++mi) {
#pragma unroll
      for (int nt3 = 0; nt3 < 7; ++nt3) {
        int n = nt3 * 16 + c;
#pragma unroll
        for (int rg = 0; rg < 4; ++rg) {
          float v = (n < 100) ? (C3[mi][nt3][rg] > 0.f ? C3[mi][nt3][rg] : 0.f)
                              : (n == 100 ? 1.0f : 0.0f);
          h1s[wv][q * 4 + rg][n] = (bf16)v;
        }
      }
      ORDER();
      f32x4 C4 = {0.f, 0.f, 0.f, 0.f};
#pragma unroll
      for (int tt = 0; tt < 4; ++tt) {
        bf16x8 A4 = *(const bf16x8*)&h1s[wv][c][tt * 32 + q * 8];
        C4 = MFMA16(A4, b4f[tt], C4);
      }
      ORDER();   // before next mi overwrites h1s
      if (c < 6) {
#pragma unroll
        for (int rg = 0; rg < 4; ++rg) {
          int slot = start + wv * 32 + mi * 16 + q * 4 + rg;
          if (slot < count) {
            float d = deltaC[((size_t)a * B_ROWS + slot) * 6 + c];
            float e = C4[rg] - d;
            sq += e * e;
          }
        }
      }
    }
#pragma unroll
    for (int off = 32; off; off >>= 1) sq += __shfl_xor(sq, off);
    if (lane == 0) s_part[wv] = sq;
  } else {
    if (lane == 0) s_part[wv] = 0.f;
  }
  __syncthreads();
  if (threadIdx.x == 0)
    partial[pslot] = s_part[0] + s_part[1] + s_part[2] + s_part[3];
}

// One-block tree reduction over 1536 per-block partials.
__global__ __launch_bounds__(256) void k_final(
    const float* __restrict__ partial, float* __restrict__ out)
{
  __shared__ float s[4];
  int t = threadIdx.x, lane = t & 63, wv = t >> 6;
  float sum = 0.f;
  for (int i = t; i < 3 * MLP_BX; i += 256) sum += partial[i];
#pragma unroll
  for (int off = 32; off; off >>= 1) sum += __shfl_xor(sum, off);
  if (lane == 0) s[wv] = sum;
  __syncthreads();
  if (t == 0) {
    double tot = (double)s[0] + s[1] + s[2] + s[3];
    out[0] = (float)(tot / (double)(B_ROWS * 6));
  }
}

extern "C" void kernel_launch(void* const* d_in, const int* in_sizes, int n_in,
                              void* d_out, int out_size, void* d_ws, size_t ws_size,
                              hipStream_t stream)
{
  const float* x  = (const float*)d_in[0];
  const float* xn = (const float*)d_in[1];
  const int*  act = (const int*)d_in[2];
  const float* W1 = (const float*)d_in[3];
  const float* b1 = (const float*)d_in[4];
  const float* W2 = (const float*)d_in[5];
  const float* b2 = (const float*)d_in[6];
  const float* W3 = (const float*)d_in[7];
  const float* b3 = (const float*)d_in[8];
  const float* W4 = (const float*)d_in[9];
  const float* b4 = (const float*)d_in[10];

  char* ws = (char*)d_ws;
  bf16*   W1t    = (bf16*)(ws + OFF_W1T);
  bf16*   W2t    = (bf16*)(ws + OFF_W2T);
  bf16*   W3t    = (bf16*)(ws + OFF_W3T);
  bf16*   W4t    = (bf16*)(ws + OFF_W4T);
  int*    cnt    = (int*)(ws + OFF_CNT);
  int*    ptrArr = (int*)(ws + OFF_PTR);
  bf16*   attC   = (bf16*)(ws + OFF_ATTC);
  float*  deltaC = (float*)(ws + OFF_DELTA);
  float*  part   = (float*)(ws + OFF_PART);

  k_prep<<<dim3(WPREP_BLOCKS + SCAN_BLOCKS), dim3(256), 0, stream>>>(
      W1, b1, W2, b2, W3, b3, W4, b4, x, W1t, W2t, W3t, W4t, cnt, ptrArr);
  k_gather2<<<dim3(B_ROWS / 256), dim3(256), 0, stream>>>(x, xn, act, ptrArr,
                                                          attC, deltaC, cnt);
  k_mlp<<<dim3(MLP_BX, 3), dim3(256), 0, stream>>>(W1t, W2t, W3t, W4t,
                                                   attC, deltaC, cnt, part);
  k_final<<<dim3(1), dim3(256), 0, stream>>>(part, (float*)d_out);
}

// Round 6
// 295.985 us; speedup vs baseline: 1.2830x; 1.0028x over previous
//
#include <hip/hip_runtime.h>
#include <hip/hip_bf16.h>

#define B_ROWS 65536
#define XD 362

typedef __bf16 bf16;
typedef __attribute__((ext_vector_type(8))) __bf16 bf16x8;
typedef __attribute__((ext_vector_type(4))) float f32x4;
typedef __attribute__((ext_vector_type(2))) float f32x2;

#define MFMA16(A, Bf, C) __builtin_amdgcn_mfma_f32_16x16x32_bf16(A, Bf, C, 0, 0, 0)
// DS ops stay ordered (HW executes a wave's DS ops in order; this stops the
// compiler reordering them); VALU/SALU/MFMA/VMEM may cross.
#define ORDER() __builtin_amdgcn_sched_barrier(0x7F)

// ---- workspace layout (bytes) ----
#define OFF_W1T   0u          // [3][112][32] bf16
#define OFF_W2T   21504u      // [3][416][128] bf16 (n=400 row = bias marker)
#define OFF_W3T   340992u     // [3][112][416] bf16
#define OFF_W4T   620544u     // [3][16][128] bf16
#define OFF_CNT   632832u     // int[3]
#define OFF_PTR   633088u     // int[65536]
#define OFF_ATTC  895232u     // [3][65536][8] bf16
#define OFF_DELTA 4040960u    // [3][65536][6] f32
#define OFF_PART  8759552u    // float[MLP_GRID] per-block partials

#define MLP_GRID 520          // >= 514 worst-case tiles; all blocks work
#define WPREP_BLOCKS 624      // 624*256 = 159744 >= 3*416*128
#define SCAN_BLOCKS 2896      // 2896*256*8 float4 == 65536*362/4 exactly

// Fused: weight transpose/pack (blocks 0..623) + flat sentinel scan (rest).
__global__ __launch_bounds__(256) void k_prep(
    const float* __restrict__ W1, const float* __restrict__ b1,
    const float* __restrict__ W2, const float* __restrict__ b2,
    const float* __restrict__ W3, const float* __restrict__ b3,
    const float* __restrict__ W4, const float* __restrict__ b4,
    const float* __restrict__ x,
    bf16* __restrict__ W1t, bf16* __restrict__ W2t,
    bf16* __restrict__ W3t, bf16* __restrict__ W4t,
    int* __restrict__ cnt, int* __restrict__ ptrArr)
{
  int bx = blockIdx.x;
  if (bx >= WPREP_BLOCKS) {
    int gid = (bx - WPREP_BLOCKS) * 256 + threadIdx.x;
    const float4* x4 = (const float4*)x;
#pragma unroll
    for (int u = 0; u < 8; ++u) {
      int i = gid + u * (SCAN_BLOCKS * 256);   // exact coverage, no bounds chk
      float4 v = x4[i];
      if (v.x == 10.0f || v.y == 10.0f || v.z == 10.0f || v.w == 10.0f) {
        int flat = i * 4;
        if (v.x == 10.0f) ptrArr[(flat    ) / XD] = (flat    ) % XD;
        if (v.y == 10.0f) ptrArr[(flat + 1) / XD] = (flat + 1) % XD;
        if (v.z == 10.0f) ptrArr[(flat + 2) / XD] = (flat + 2) % XD;
        if (v.w == 10.0f) ptrArr[(flat + 3) / XD] = (flat + 3) % XD;
      }
    }
    return;
  }
  int i = bx * 256 + threadIdx.x;
  if (i == 0) { cnt[0] = 0; cnt[1] = 0; cnt[2] = 0; }
  if (i < 3*416*128) {               // W2t [n=416][k=128]
    int k = i & 127; int rn = i >> 7; int n = rn % 416; int a = rn / 416;
    float v = 0.f;
    if (n < 400) {
      if (k < 100) v = W2[(a*100 + k)*400 + n];
      else if (k == 100) v = b2[a*400 + n];
    } else if (n == 400) {
      v = (k == 100) ? 1.0f : 0.0f;  // bias-marker row: h2[*][400] = h1[*][100] = 1
    }
    W2t[i] = (bf16)v;
  }
  if (i < 3*112*416) {               // W3t [n=112][k=416]
    int k = i % 416; int rn = i / 416; int n = rn % 112; int a = rn / 112;
    float v = 0.f;
    if (n < 100) {
      if (k < 400) v = W3[(a*400 + k)*100 + n];
      else if (k == 400) v = b3[a*100 + n];
    }
    W3t[i] = (bf16)v;
  }
  if (i < 3*112*32) {                // W1t [n=112][k=32]
    int k = i & 31; int rn = i >> 5; int n = rn % 112; int a = rn / 112;
    float v = 0.f;
    if (n < 100) {
      if (k < 6) v = W1[(a*6 + k)*100 + n];
      else if (k == 6) v = b1[a*100 + n];
    }
    W1t[i] = (bf16)v;
  }
  if (i < 3*16*128) {                // W4t [n=16][k=128]
    int k = i & 127; int rn = i >> 7; int n = rn & 15; int a = rn >> 4;
    float v = 0.f;
    if (n < 6) {
      if (k < 100) v = W4[(a*100 + k)*6 + n];
      else if (k == 100) v = b4[a*6 + n];
    }
    W4t[i] = (bf16)v;
  }
}

// One thread per row: gather 6 cells from x/xn, per-wave ballot compaction
// into action-sorted arrays (3 native int atomics per wave).
__global__ __launch_bounds__(256) void k_gather2(
    const float* __restrict__ x, const float* __restrict__ xn,
    const int* __restrict__ act, const int* __restrict__ ptrArr,
    bf16* __restrict__ attC, float* __restrict__ deltaC, int* __restrict__ cnt)
{
  int row = blockIdx.x * 256 + threadIdx.x;
  int lane = threadIdx.x & 63;
  int p = ptrArr[row];
  if (p < 20 || p > 342) p = 20;   // reference guarantees 20..342
  const float* xr = x  + (size_t)row * XD;
  const float* nr = xn + (size_t)row * XD;
  int cells[6] = {0, p, p - 19, p + 19, p - 1, p + 1};
  float av[6], dv[6];
#pragma unroll
  for (int i = 0; i < 6; ++i) {
    av[i] = xr[cells[i]];
    dv[i] = nr[cells[i]] - av[i];
  }
  int a = act[row];
  unsigned long long m0 = __ballot(a == 0);
  unsigned long long m1 = __ballot(a == 1);
  unsigned long long m2 = __ballot(a == 2);
  int b0 = 0, b1 = 0, b2 = 0;
  if (lane == 0) {
    b0 = atomicAdd(&cnt[0], (int)__popcll(m0));
    b1 = atomicAdd(&cnt[1], (int)__popcll(m1));
    b2 = atomicAdd(&cnt[2], (int)__popcll(m2));
  }
  b0 = __shfl(b0, 0); b1 = __shfl(b1, 0); b2 = __shfl(b2, 0);
  unsigned long long lt = (1ull << lane) - 1ull;
  unsigned long long ma = (a == 0) ? m0 : (a == 1) ? m1 : m2;
  int base            = (a == 0) ? b0 : (a == 1) ? b1 : b2;
  int slot = base + (int)__popcll(ma & lt);
  size_t rb = (size_t)a * B_ROWS + slot;
  bf16x8 av8;
#pragma unroll
  for (int i = 0; i < 6; ++i) av8[i] = (bf16)av[i];
  av8[6] = (bf16)1.0f;   // bias marker
  av8[7] = (bf16)0.0f;
  *(bf16x8*)(attC + rb * 8) = av8;
  f32x2 d01 = {dv[0], dv[1]}, d23 = {dv[2], dv[3]}, d45 = {dv[4], dv[5]};
  *(f32x2*)(deltaC + rb * 6)     = d01;
  *(f32x2*)(deltaC + rb * 6 + 2) = d23;
  *(f32x2*)(deltaC + rb * 6 + 4) = d45;
}

// Flat 520-block grid; each block maps itself to (action, 128-row tile) from
// the device-side counts -> every block does real work, even CU distribution.
// K-loop: 13 uniform iterations (bias-marker n-tile materialized in W2t).
// Software pipeline: all 15 next-use fragment loads issued at iteration top,
// sched_barrier(0) pins them above the MFMA block (compiler cannot sink them
// to uses) -> load->use distance ~ one L2-MFMA + LDS roundtrip.
__global__ __launch_bounds__(256, 2) void k_mlp(
    const bf16* __restrict__ W1t, const bf16* __restrict__ W2t,
    const bf16* __restrict__ W3t, const bf16* __restrict__ W4t,
    const bf16* __restrict__ attC, const float* __restrict__ deltaC,
    const int* __restrict__ cnt, float* __restrict__ partial)
{
  int c0 = cnt[0], c1 = cnt[1], c2 = cnt[2];
  int T0 = (c0 + 127) >> 7, T1 = (c1 + 127) >> 7, T2 = (c2 + 127) >> 7;
  int b = blockIdx.x;
  int a, tile, count;
  if (b < T0)           { a = 0; tile = b;            count = c0; }
  else if (b < T0 + T1) { a = 1; tile = b - T0;       count = c1; }
  else if (b < T0 + T1 + T2) { a = 2; tile = b - T0 - T1; count = c2; }
  else { if (threadIdx.x == 0) partial[b] = 0.f; return; }
  int start = tile << 7;

  __shared__ __align__(16) bf16 h1s[4][16][136];   // per-wave scratch
  __shared__ __align__(16) bf16 tr[4][2][16][56];  // per-wave,per-mtile chunk
  __shared__ float s_part[4];
  int wv = threadIdx.x >> 6, lane = threadIdx.x & 63;
  int q = lane >> 4, c = lane & 15;

  const bf16* W1a = W1t + a * 112 * 32;
  const bf16* W2a = W2t + a * 416 * 128;
  const bf16* W3a = W3t + a * 112 * 416;
  const bf16* W4a = W4t + a * 16 * 128;

  // zero this wave's h1s pad cols 112..127 (read as A-frag k=96..127)
  for (int i = lane; i < 16 * 16; i += 64)
    h1s[wv][i >> 4][112 + (i & 15)] = (bf16)0.0f;

  // ---- L1: 6(+bias)->100, per m-tile, A2 frags kept in registers ----
  bf16x8 A2[2][4];
#pragma unroll
  for (int mi = 0; mi < 2; ++mi) {
    bf16x8 aAtt;
#pragma unroll
    for (int i = 0; i < 8; ++i) aAtt[i] = (bf16)0.0f;
    int slot = start + wv * 32 + mi * 16 + c;
    if (q == 0 && slot < count)
      aAtt = *(const bf16x8*)(attC + ((size_t)a * B_ROWS + slot) * 8);
#pragma unroll
    for (int nt = 0; nt < 7; ++nt) {
      bf16x8 bw = *(const bf16x8*)(W1a + (nt * 16 + c) * 32 + q * 8);
      f32x4 C = {0.f, 0.f, 0.f, 0.f};
      C = MFMA16(aAtt, bw, C);
      int n = nt * 16 + c;
#pragma unroll
      for (int rg = 0; rg < 4; ++rg) {
        float v = (n < 100) ? (C[rg] > 0.f ? C[rg] : 0.f)
                            : (n == 100 ? 1.0f : 0.0f);
        h1s[wv][q * 4 + rg][n] = (bf16)v;
      }
    }
    ORDER();
#pragma unroll
    for (int tt = 0; tt < 4; ++tt)
      A2[mi][tt] = *(const bf16x8*)&h1s[wv][c][tt * 32 + q * 8];
    ORDER();   // before next mi overwrites h1s
  }

  f32x4 C3[2][7];
#pragma unroll
  for (int mi = 0; mi < 2; ++mi)
#pragma unroll
    for (int i = 0; i < 7; ++i) C3[mi][i] = (f32x4){0.f, 0.f, 0.f, 0.f};

  // prologue: W2 fragments for t=0
  bf16x8 b2f[2][4];
#pragma unroll
  for (int half = 0; half < 2; ++half)
#pragma unroll
    for (int tt = 0; tt < 4; ++tt)
      b2f[half][tt] = *(const bf16x8*)(W2a + (half * 16 + c) * 128 + tt * 32 + q * 8);

  // ---- L2+L3 fused, 13 uniform iterations, pipelined ----
#pragma unroll 1
  for (int t = 0; t < 13; ++t) {
    // issue ALL fragment loads for this iteration's L3 and next's L2 up front
    bf16x8 w3f[7];
#pragma unroll
    for (int nt3 = 0; nt3 < 7; ++nt3)
      w3f[nt3] = *(const bf16x8*)(W3a + (nt3 * 16 + c) * 416 + t * 32 + q * 8);
    int tn = (t < 12) ? t + 1 : 12;       // dummy reload at t=12 (uniform loop)
    bf16x8 b2n[2][4];
#pragma unroll
    for (int half = 0; half < 2; ++half)
#pragma unroll
      for (int tt = 0; tt < 4; ++tt)
        b2n[half][tt] = *(const bf16x8*)(W2a + ((2 * tn + half) * 16 + c) * 128 + tt * 32 + q * 8);
    __builtin_amdgcn_sched_barrier(0);    // pin loads ABOVE the compute block

    // L2: h2 chunk (32 cols) for both m-tiles, using b2f (already resident)
#pragma unroll
    for (int mi = 0; mi < 2; ++mi)
#pragma unroll
      for (int half = 0; half < 2; ++half) {
        f32x4 C = {0.f, 0.f, 0.f, 0.f};
#pragma unroll
        for (int tt = 0; tt < 4; ++tt)
          C = MFMA16(A2[mi][tt], b2f[half][tt], C);
#pragma unroll
        for (int rg = 0; rg < 4; ++rg) {
          float v = C[rg] > 0.f ? C[rg] : 0.f;
          tr[wv][mi][q * 4 + rg][half * 16 + c] = (bf16)v;
        }
      }
    ORDER();
    bf16x8 A3a = *(const bf16x8*)&tr[wv][0][c][q * 8];
    bf16x8 A3b = *(const bf16x8*)&tr[wv][1][c][q * 8];
#pragma unroll
    for (int nt3 = 0; nt3 < 7; ++nt3) {
      C3[0][nt3] = MFMA16(A3a, w3f[nt3], C3[0][nt3]);
      C3[1][nt3] = MFMA16(A3b, w3f[nt3], C3[1][nt3]);
    }
    ORDER();
    // rotate prefetched W2 fragments
#pragma unroll
    for (int half = 0; half < 2; ++half)
#pragma unroll
      for (int tt = 0; tt < 4; ++tt)
        b2f[half][tt] = b2n[half][tt];
  }

  // ---- L4: 100(+bias)->6 + MSE, per m-tile (h1s serial reuse) ----
  bf16x8 b4f[4];
#pragma unroll
  for (int tt = 0; tt < 4; ++tt)
    b4f[tt] = *(const bf16x8*)(W4a + c * 128 + tt * 32 + q * 8);
  float sq = 0.f;
#pragma unroll
  for (int mi = 0; mi < 2; ++mi) {
#pragma unroll
    for (int nt3 = 0; nt3 < 7; ++nt3) {
      int n = nt3 * 16 + c;
#pragma unroll
      for (int rg = 0; rg < 4; ++rg) {
        float v = (n < 100) ? (C3[mi][nt3][rg] > 0.f ? C3[mi][nt3][rg] : 0.f)
                            : (n == 100 ? 1.0f : 0.0f);
        h1s[wv][q * 4 + rg][n] = (bf16)v;
      }
    }
    ORDER();
    f32x4 C4 = {0.f, 0.f, 0.f, 0.f};
#pragma unroll
    for (int tt = 0; tt < 4; ++tt) {
      bf16x8 A4 = *(const bf16x8*)&h1s[wv][c][tt * 32 + q * 8];
      C4 = MFMA16(A4, b4f[tt], C4);
    }
    ORDER();   // before next mi overwrites h1s
    if (c < 6) {
#pragma unroll
      for (int rg = 0; rg < 4; ++rg) {
        int slot = start + wv * 32 + mi * 16 + q * 4 + rg;
        if (slot < count) {
          float d = deltaC[((size_t)a * B_ROWS + slot) * 6 + c];
          float e = C4[rg] - d;
          sq += e * e;
        }
      }
    }
  }
#pragma unroll
  for (int off = 32; off; off >>= 1) sq += __shfl_xor(sq, off);
  if (lane == 0) s_part[wv] = sq;
  __syncthreads();
  if (threadIdx.x == 0)
    partial[b] = s_part[0] + s_part[1] + s_part[2] + s_part[3];
}

// One-block tree reduction over per-block partials.
__global__ __launch_bounds__(256) void k_final(
    const float* __restrict__ partial, float* __restrict__ out)
{
  __shared__ float s[4];
  int t = threadIdx.x, lane = t & 63, wv = t >> 6;
  float sum = 0.f;
  for (int i = t; i < MLP_GRID; i += 256) sum += partial[i];
#pragma unroll
  for (int off = 32; off; off >>= 1) sum += __shfl_xor(sum, off);
  if (lane == 0) s[wv] = sum;
  __syncthreads();
  if (t == 0) {
    double tot = (double)s[0] + s[1] + s[2] + s[3];
    out[0] = (float)(tot / (double)(B_ROWS * 6));
  }
}

extern "C" void kernel_launch(void* const* d_in, const int* in_sizes, int n_in,
                              void* d_out, int out_size, void* d_ws, size_t ws_size,
                              hipStream_t stream)
{
  const float* x  = (const float*)d_in[0];
  const float* xn = (const float*)d_in[1];
  const int*  act = (const int*)d_in[2];
  const float* W1 = (const float*)d_in[3];
  const float* b1 = (const float*)d_in[4];
  const float* W2 = (const float*)d_in[5];
  const float* b2 = (const float*)d_in[6];
  const float* W3 = (const float*)d_in[7];
  const float* b3 = (const float*)d_in[8];
  const float* W4 = (const float*)d_in[9];
  const float* b4 = (const float*)d_in[10];

  char* ws = (char*)d_ws;
  bf16*   W1t    = (bf16*)(ws + OFF_W1T);
  bf16*   W2t    = (bf16*)(ws + OFF_W2T);
  bf16*   W3t    = (bf16*)(ws + OFF_W3T);
  bf16*   W4t    = (bf16*)(ws + OFF_W4T);
  int*    cnt    = (int*)(ws + OFF_CNT);
  int*    ptrArr = (int*)(ws + OFF_PTR);
  bf16*   attC   = (bf16*)(ws + OFF_ATTC);
  float*  deltaC = (float*)(ws + OFF_DELTA);
  float*  part   = (float*)(ws + OFF_PART);

  k_prep<<<dim3(WPREP_BLOCKS + SCAN_BLOCKS), dim3(256), 0, stream>>>(
      W1, b1, W2, b2, W3, b3, W4, b4, x, W1t, W2t, W3t, W4t, cnt, ptrArr);
  k_gather2<<<dim3(B_ROWS / 256), dim3(256), 0, stream>>>(x, xn, act, ptrArr,
                                                          attC, deltaC, cnt);
  k_mlp<<<dim3(MLP_GRID), dim3(256), 0, stream>>>(W1t, W2t, W3t, W4t,
                                                  attC, deltaC, cnt, part);
  k_final<<<dim3(1), dim3(256), 0, stream>>>(part, (float*)d_out);
}